// Round 8
// baseline (2047.440 us; speedup 1.0000x reference)
//
#include <hip/hip_runtime.h>

#define NNODES 100000
#define NEDGES 1600000
#define NGRAPHS 2048
#define BN_EPS 1e-5f

// ---------------- CSR build ----------------
__global__ __launch_bounds__(256) void deg_kernel(const int* __restrict__ dstA,
                                                  int* __restrict__ deg) {
    int e = blockIdx.x * 256 + threadIdx.x;
    if (e < NEDGES) atomicAdd(&deg[dstA[e]], 1);
}

// ---- 3-phase parallel exclusive scan of deg -> rowptr/cursor ----
__global__ __launch_bounds__(256) void scan1_kernel(const int* __restrict__ deg,
                                                    int* __restrict__ partials) {
    int b = blockIdx.x;
    int i = b * 256 + threadIdx.x;
    int v = (i < NNODES) ? deg[i] : 0;
    __shared__ int wsum[4];
#pragma unroll
    for (int off = 32; off; off >>= 1) v += __shfl_down(v, off);
    if ((threadIdx.x & 63) == 0) wsum[threadIdx.x >> 6] = v;
    __syncthreads();
    if (threadIdx.x == 0) partials[b] = wsum[0] + wsum[1] + wsum[2] + wsum[3];
}

__global__ __launch_bounds__(512) void scan2_kernel(int* __restrict__ partials, int nb) {
    __shared__ int s[512];
    int t = threadIdx.x;
    int v = (t < nb) ? partials[t] : 0;
    s[t] = v;
    __syncthreads();
    for (int off = 1; off < 512; off <<= 1) {
        int u = (t >= off) ? s[t - off] : 0;
        __syncthreads();
        s[t] += u;
        __syncthreads();
    }
    if (t < nb) partials[t] = s[t] - v;  // exclusive
}

__global__ __launch_bounds__(256) void scan3_kernel(const int* __restrict__ deg,
                                                    const int* __restrict__ partials,
                                                    int* __restrict__ rowptr,
                                                    int* __restrict__ cursor) {
    int b = blockIdx.x;
    int t = threadIdx.x;
    int i = b * 256 + t;
    __shared__ int s[256];
    int v = (i < NNODES) ? deg[i] : 0;
    s[t] = v;
    __syncthreads();
    for (int off = 1; off < 256; off <<= 1) {
        int u = (t >= off) ? s[t - off] : 0;
        __syncthreads();
        s[t] += u;
        __syncthreads();
    }
    if (i < NNODES) {
        int ex = partials[b] + s[t] - v;
        rowptr[i] = ex;
        cursor[i] = ex;
    }
    if (b == 0 && t == 0) rowptr[NNODES] = NEDGES;  // sum(deg) == NEDGES
}

__global__ __launch_bounds__(256) void fill_kernel(const int* __restrict__ srcA,
                                                   const int* __restrict__ dstA,
                                                   int* __restrict__ cursor,
                                                   int* __restrict__ adj) {
    int e = blockIdx.x * 256 + threadIdx.x;
    if (e < NEDGES) {
        int d = dstA[e];
        int loc = atomicAdd(&cursor[d], 1);
        adj[loc] = srcA[e];
    }
}

// ---- graph boundaries from sorted batch: gstart[g] = first node of graph g ----
__global__ __launch_bounds__(256) void gbound_kernel(const int* __restrict__ batch,
                                                     int* __restrict__ gstart) {
    int i = blockIdx.x * 256 + threadIdx.x;
    if (i >= NNODES) return;
    int b = batch[i];
    int bp = (i == 0) ? -1 : batch[i - 1];
    for (int g = bp + 1; g <= b; ++g) gstart[g] = i;
    if (i == NNODES - 1)
        for (int g = b + 1; g <= NGRAPHS; ++g) gstart[g] = NNODES;
}

// ------- gather aggregation: agg[n] = x[n] + sum_{s in adj[n]} x[s] (+bias) -------
template <int DIM, int CHUNK, int OSTRIDE>
__global__ __launch_bounds__(256) void gather_kernel(const float* __restrict__ x,
                                                     const int* __restrict__ rowptr,
                                                     const int* __restrict__ adj,
                                                     float* __restrict__ agg,
                                                     const float* __restrict__ bias) {
    constexpr int PE = DIM / CHUNK;
    int gid = blockIdx.x * 256 + threadIdx.x;
    if (gid >= NNODES * PE) return;
    int node = gid / PE;
    int c = gid - node * PE;
    const int beg = rowptr[node];
    const int end = rowptr[node + 1];
    if (CHUNK == 4) {
        const float4* xp = (const float4*)x;
        float4 acc = xp[(size_t)node * PE + c];
        for (int i = beg; i < end; ++i) {
            int s = adj[i];
            float4 v = xp[(size_t)s * PE + c];
            acc.x += v.x;
            acc.y += v.y;
            acc.z += v.z;
            acc.w += v.w;
        }
        if (bias) {
            float4 b = *(const float4*)&bias[c * 4];
            acc.x += b.x; acc.y += b.y; acc.z += b.z; acc.w += b.w;
        }
        *(float4*)&agg[(size_t)node * OSTRIDE + c * 4] = acc;
    } else {
        const float2* xp = (const float2*)x;
        float2 acc = xp[(size_t)node * PE + c];
        for (int i = beg; i < end; ++i) {
            int s = adj[i];
            float2 v = xp[(size_t)s * PE + c];
            acc.x += v.x;
            acc.y += v.y;
        }
        *(float2*)&agg[(size_t)node * OSTRIDE + c * 2] = acc;
    }
}

// ---------------- BN stats (standalone, used once for L2) ----------------
template <int N>
__global__ __launch_bounds__(256) void bnstats_kernel(const float* __restrict__ h,
                                                      float* __restrict__ sums) {
    constexpr int SHIFT = (N == 128) ? 7 : 8;
    int t = blockIdx.x * 256 + threadIdx.x;
    int col = t & (N - 1);
    int slice = t >> SHIFT;
    float s = 0.f, s2 = 0.f;
    for (int r = slice; r < NNODES; r += 256) {
        float v = h[(size_t)r * N + col];
        s += v;
        s2 += v * v;
    }
    atomicAdd(&sums[col], s);
    atomicAdd(&sums[N + col], s2);
}

__global__ void bnfinal_kernel(const float* __restrict__ sums, const float* __restrict__ gamma,
                               const float* __restrict__ beta, float* __restrict__ scale,
                               float* __restrict__ shift, int N, float invM) {
    int c = blockIdx.x * blockDim.x + threadIdx.x;
    if (c < N) {
        float mean = sums[c] * invM;
        float var = sums[N + c] * invM - mean * mean;
        float sc = gamma[c] * rsqrtf(var + BN_EPS);
        scale[c] = sc;
        shift[c] = beta[c] - mean * sc;
    }
}

__device__ __forceinline__ void fma44(float (&cc)[4][4], const float4& a, const float4& b) {
    cc[0][0] += a.x * b.x; cc[0][1] += a.x * b.y; cc[0][2] += a.x * b.z; cc[0][3] += a.x * b.w;
    cc[1][0] += a.y * b.x; cc[1][1] += a.y * b.y; cc[1][2] += a.y * b.z; cc[1][3] += a.y * b.w;
    cc[2][0] += a.z * b.x; cc[2][1] += a.z * b.y; cc[2][2] += a.z * b.z; cc[2][3] += a.z * b.w;
    cc[3][0] += a.w * b.x; cc[3][1] += a.w * b.y; cc[3][2] += a.w * b.z; cc[3][3] += a.w * b.w;
}

// ---------------- 128x128 tile fp32 GEMM, 8x8/thread (2x2 quadrants), prefetched ---------
// R7 evidence: 8x4 was LDS-byte-bound (1.5 B/FMA-lane at ~85 B/cyc/CU supply). 8x8 cuts
// to 1.0 B/FMA-lane. R4's 8x8 failure was LDS *latency* (no prefetch, 3 waves/SIMD);
// value-prefetch of the next kk (R5's proven fix) hides it within-wave.
// A: M x K row-major (K = padded stride, K%4==0). W: Kw x N (rows >= Kw read as 0).
template <bool BNRELU_A, bool RELU_OUT, bool FUSE_STATS>
__global__ __launch_bounds__(256, 3) void gemm128x128_kernel(
    const float* __restrict__ A, const float* __restrict__ W, const float* __restrict__ bias,
    const float* __restrict__ scale, const float* __restrict__ shift, float* __restrict__ C,
    float* __restrict__ stats, int M, int K, int Kw, int N) {
    __shared__ __align__(16) float As[16][132];  // [k][m], 132 stride
    __shared__ __align__(16) float Bs[16][128];  // [k][n]
    __shared__ float sstat[256];                 // 128 sum + 128 sumsq
    const int tid = threadIdx.x;
    const int tx = tid & 15;
    const int ty = tid >> 4;
    const int m0 = blockIdx.x * 128;
    const int n0 = blockIdx.y * 128;

    if (FUSE_STATS) sstat[tid] = 0.f;  // synced by first k-loop barrier

    float c[2][2][4][4] = {};

    for (int k0 = 0; k0 < K; k0 += 16) {
        // ---- stage A tile (128 rows x 16 k) transposed into As[k][m] ----
#pragma unroll
        for (int i = 0; i < 2; ++i) {
            int lin4 = tid + i * 256;  // [0,512)
            int row = lin4 >> 2;       // 0..127
            int kq = lin4 & 3;         // k-quad
            int gm = m0 + row;
            float4 v = make_float4(0.f, 0.f, 0.f, 0.f);
            if (gm < M) v = *(const float4*)&A[(size_t)gm * K + k0 + kq * 4];
            if (BNRELU_A) {
                int gk = k0 + kq * 4;
                v.x = fmaxf(v.x * scale[gk + 0] + shift[gk + 0], 0.f);
                v.y = fmaxf(v.y * scale[gk + 1] + shift[gk + 1], 0.f);
                v.z = fmaxf(v.z * scale[gk + 2] + shift[gk + 2], 0.f);
                v.w = fmaxf(v.w * scale[gk + 3] + shift[gk + 3], 0.f);
            }
            As[kq * 4 + 0][row] = v.x;
            As[kq * 4 + 1][row] = v.y;
            As[kq * 4 + 2][row] = v.z;
            As[kq * 4 + 3][row] = v.w;
        }
        // ---- stage W tile (16 k x 128 n): 2 float4 per thread; guard by Kw ----
#pragma unroll
        for (int i = 0; i < 2; ++i) {
            int lin4 = tid + i * 256;  // [0,512)
            int kr = lin4 >> 5;        // 0..15
            int nq = lin4 & 31;        // 0..31
            int gk = k0 + kr;
            float4 v = make_float4(0.f, 0.f, 0.f, 0.f);
            if (gk < Kw) v = *(const float4*)&W[(size_t)gk * N + n0 + nq * 4];
            *(float4*)&Bs[kr][nq * 4] = v;
        }
        __syncthreads();
        // ---- inner product, next-kk value prefetch ----
        float4 a0 = *(const float4*)&As[0][ty * 4];
        float4 a1 = *(const float4*)&As[0][64 + ty * 4];
        float4 b0 = *(const float4*)&Bs[0][tx * 4];
        float4 b1 = *(const float4*)&Bs[0][64 + tx * 4];
#pragma unroll
        for (int kk = 0; kk < 16; ++kk) {
            float4 na0, na1, nb0, nb1;
            if (kk < 15) {
                na0 = *(const float4*)&As[kk + 1][ty * 4];
                na1 = *(const float4*)&As[kk + 1][64 + ty * 4];
                nb0 = *(const float4*)&Bs[kk + 1][tx * 4];
                nb1 = *(const float4*)&Bs[kk + 1][64 + tx * 4];
            }
            fma44(c[0][0], a0, b0);
            fma44(c[0][1], a0, b1);
            fma44(c[1][0], a1, b0);
            fma44(c[1][1], a1, b1);
            if (kk < 15) {
                a0 = na0;
                a1 = na1;
                b0 = nb0;
                b1 = nb1;
            }
        }
        __syncthreads();
    }

    // ---- epilogue: bias (+relu) store, optional fused column stats ----
    float s_sum[8] = {}, s_sq[8] = {};
    const bool hasb = (bias != nullptr);
    float4 bv[2] = {make_float4(0.f, 0.f, 0.f, 0.f), make_float4(0.f, 0.f, 0.f, 0.f)};
    if (hasb) {
        bv[0] = *(const float4*)&bias[n0 + tx * 4];
        bv[1] = *(const float4*)&bias[n0 + 64 + tx * 4];
    }
#pragma unroll
    for (int qa = 0; qa < 2; ++qa) {
#pragma unroll
        for (int i = 0; i < 4; ++i) {
            int gm = m0 + qa * 64 + ty * 4 + i;
            if (gm >= M) continue;
#pragma unroll
            for (int qb = 0; qb < 2; ++qb) {
                int gn = n0 + qb * 64 + tx * 4;
                float4 v;
                v.x = c[qa][qb][i][0] + bv[qb].x;
                v.y = c[qa][qb][i][1] + bv[qb].y;
                v.z = c[qa][qb][i][2] + bv[qb].z;
                v.w = c[qa][qb][i][3] + bv[qb].w;
                if (RELU_OUT) {
                    v.x = fmaxf(v.x, 0.f); v.y = fmaxf(v.y, 0.f);
                    v.z = fmaxf(v.z, 0.f); v.w = fmaxf(v.w, 0.f);
                }
                *(float4*)&C[(size_t)gm * N + gn] = v;
                if (FUSE_STATS) {
                    s_sum[qb * 4 + 0] += v.x; s_sq[qb * 4 + 0] += v.x * v.x;
                    s_sum[qb * 4 + 1] += v.y; s_sq[qb * 4 + 1] += v.y * v.y;
                    s_sum[qb * 4 + 2] += v.z; s_sq[qb * 4 + 2] += v.z * v.z;
                    s_sum[qb * 4 + 3] += v.w; s_sq[qb * 4 + 3] += v.w * v.w;
                }
            }
        }
    }
    if (FUSE_STATS) {
#pragma unroll
        for (int qb = 0; qb < 2; ++qb)
#pragma unroll
            for (int j = 0; j < 4; ++j) {
                int cl = qb * 64 + tx * 4 + j;
                atomicAdd(&sstat[cl], s_sum[qb * 4 + j]);
                atomicAdd(&sstat[128 + cl], s_sq[qb * 4 + j]);
            }
        __syncthreads();
        if (tid < 128) {
            atomicAdd(&stats[n0 + tid], sstat[tid]);
            atomicAdd(&stats[N + n0 + tid], sstat[128 + tid]);
        }
    }
}

// ---------------- 64x64 tile fp32 GEMM (fc0/fc1 head) ----------------
template <bool RELU_OUT>
__global__ __launch_bounds__(256) void gemm64_kernel(const float* __restrict__ A,
                                                     const float* __restrict__ W,
                                                     const float* __restrict__ bias,
                                                     float* __restrict__ C, int M, int K, int N) {
    __shared__ __align__(16) float As[16][68];
    __shared__ __align__(16) float Bs[16][64];
    const int tid = threadIdx.x;
    const int tx = tid & 15;
    const int ty = tid >> 4;
    const int m0 = blockIdx.x * 64;
    const int n0 = blockIdx.y * 64;

    float c[4][4] = {};

    for (int k0 = 0; k0 < K; k0 += 16) {
#pragma unroll
        for (int i = 0; i < 4; ++i) {
            int lin = tid + i * 256;
            int m = lin >> 4;
            int k = lin & 15;
            int gm = m0 + m;
            int gk = k0 + k;
            float v = 0.f;
            if (gm < M && gk < K) v = A[(size_t)gm * K + gk];
            As[k][m] = v;
        }
#pragma unroll
        for (int i = 0; i < 4; ++i) {
            int lin = tid + i * 256;
            int k = lin >> 6;
            int n = lin & 63;
            int gk = k0 + k;
            float v = 0.f;
            if (gk < K) v = W[(size_t)gk * N + n0 + n];
            Bs[k][n] = v;
        }
        __syncthreads();
#pragma unroll
        for (int kk = 0; kk < 16; ++kk) {
            float4 a = *(const float4*)&As[kk][ty * 4];
            float4 b = *(const float4*)&Bs[kk][tx * 4];
            c[0][0] += a.x * b.x; c[0][1] += a.x * b.y; c[0][2] += a.x * b.z; c[0][3] += a.x * b.w;
            c[1][0] += a.y * b.x; c[1][1] += a.y * b.y; c[1][2] += a.y * b.z; c[1][3] += a.y * b.w;
            c[2][0] += a.z * b.x; c[2][1] += a.z * b.y; c[2][2] += a.z * b.z; c[2][3] += a.z * b.w;
            c[3][0] += a.w * b.x; c[3][1] += a.w * b.y; c[3][2] += a.w * b.z; c[3][3] += a.w * b.w;
        }
        __syncthreads();
    }

#pragma unroll
    for (int i = 0; i < 4; ++i) {
        int gm = m0 + ty * 4 + i;
        if (gm >= M) continue;
#pragma unroll
        for (int j = 0; j < 4; ++j) {
            int gn = n0 + tx * 4 + j;
            float v = c[i][j] + bias[gn];
            if (RELU_OUT) v = fmaxf(v, 0.f);
            C[(size_t)gm * N + gn] = v;
        }
    }
}

// ---- segmented pool over sorted batch ----
__global__ __launch_bounds__(128) void pool_seg_kernel(const float* __restrict__ h,
                                                       const int* __restrict__ gstart,
                                                       float* __restrict__ g) {
    int gr = blockIdx.x;
    int t = threadIdx.x;  // column 0..127
    int beg = gstart[gr];
    int end = gstart[gr + 1];
    float acc = 0.f;
    for (int r = beg; r < end; ++r) acc += h[(size_t)r * 128 + t];
    g[(size_t)gr * 128 + t] = acc;
}

extern "C" void kernel_launch(void* const* d_in, const int* in_sizes, int n_in, void* d_out,
                              int out_size, void* d_ws, size_t ws_size, hipStream_t stream) {
    const float* x = (const float*)d_in[0];
    const int* ei = (const int*)d_in[1];
    const int* batch = (const int*)d_in[2];
    const int* srcA = ei;
    const int* dstA = ei + NEDGES;

    const float* g0_w1 = (const float*)d_in[3];
    const float* g0_b1 = (const float*)d_in[4];
    const float* g0_ga = (const float*)d_in[5];
    const float* g0_be = (const float*)d_in[6];
    const float* g0_w2 = (const float*)d_in[7];
    const float* g0_b2 = (const float*)d_in[8];
    const float* g1_w1 = (const float*)d_in[9];
    const float* g1_b1 = (const float*)d_in[10];
    const float* g1_ga = (const float*)d_in[11];
    const float* g1_be = (const float*)d_in[12];
    const float* g1_w2 = (const float*)d_in[13];
    const float* g1_b2 = (const float*)d_in[14];
    const float* g2_w1 = (const float*)d_in[15];
    const float* g2_b1 = (const float*)d_in[16];
    const float* g2_ga = (const float*)d_in[17];
    const float* g2_be = (const float*)d_in[18];
    const float* g2_w2 = (const float*)d_in[19];
    const float* g2_b2 = (const float*)d_in[20];
    const float* fc0_w = (const float*)d_in[21];
    const float* fc0_b = (const float*)d_in[22];
    const float* fc1_w = (const float*)d_in[23];
    const float* fc1_b = (const float*)d_in[24];

    // --- workspace layout (~222 MB) ---
    float* ws = (float*)d_ws;
    const size_t BUF = (size_t)NNODES * 256;
    float* R0 = ws;
    float* R1 = R0 + BUF;
    float* stats = R1 + BUF;                         // 2*256
    float* scsh = stats + 512;                       // 2*256 (scale, shift)
    float* g = scsh + 512;                           // 2048*128 pooled
    float* gh = g + (size_t)NGRAPHS * 128;           // 2048*1024 fc hidden
    int* deg = (int*)(gh + (size_t)NGRAPHS * 1024);  // NNODES
    int* rowptr = deg + NNODES;                      // NNODES+1
    int* cursor = rowptr + NNODES + 4;               // NNODES
    int* adj = cursor + NNODES;                      // NEDGES
    int* partials = adj + NEDGES;                    // 391
    int* gstart = partials + 512;                    // NGRAPHS+1

    const int MB = (NNODES + 127) / 128;  // 782 row-blocks
    const int NB = (NNODES + 255) / 256;  // 391 scan blocks

    // --- build CSR + graph bounds once ---
    hipMemsetAsync(deg, 0, NNODES * sizeof(int), stream);
    deg_kernel<<<(NEDGES + 255) / 256, 256, 0, stream>>>(dstA, deg);
    scan1_kernel<<<NB, 256, 0, stream>>>(deg, partials);
    scan2_kernel<<<1, 512, 0, stream>>>(partials, NB);
    scan3_kernel<<<NB, 256, 0, stream>>>(deg, partials, rowptr, cursor);
    fill_kernel<<<(NEDGES + 255) / 256, 256, 0, stream>>>(srcA, dstA, cursor, adj);
    gbound_kernel<<<NB, 256, 0, stream>>>(batch, gstart);

    // ================= Layer 0 (66 -> 128 -> 128) =================
    gather_kernel<66, 2, 68><<<(NNODES * 33 + 255) / 256, 256, 0, stream>>>(x, rowptr, adj, R0,
                                                                            nullptr);
    hipMemsetAsync(stats, 0, 2 * 128 * sizeof(float), stream);
    gemm128x128_kernel<false, false, true><<<dim3(MB, 1), 256, 0, stream>>>(
        R0, g0_w1, g0_b1, nullptr, nullptr, R1, stats, NNODES, 68, 66, 128);
    bnfinal_kernel<<<1, 128, 0, stream>>>(stats, g0_ga, g0_be, scsh, scsh + 128, 128, 1.0f / NNODES);
    gemm128x128_kernel<true, true, false><<<dim3(MB, 1), 256, 0, stream>>>(
        R1, g0_w2, g0_b2, scsh, scsh + 128, R0, nullptr, NNODES, 128, 128, 128);

    // ================= Layer 1 (128 -> 256 -> 256) =================
    gather_kernel<128, 4, 128><<<(NNODES * 32 + 255) / 256, 256, 0, stream>>>(R0, rowptr, adj, R1,
                                                                              nullptr);
    hipMemsetAsync(stats, 0, 2 * 256 * sizeof(float), stream);
    gemm128x128_kernel<false, false, true><<<dim3(MB, 2), 256, 0, stream>>>(
        R1, g1_w1, g1_b1, nullptr, nullptr, R0, stats, NNODES, 128, 128, 256);
    bnfinal_kernel<<<1, 256, 0, stream>>>(stats, g1_ga, g1_be, scsh, scsh + 256, 256, 1.0f / NNODES);
    gemm128x128_kernel<true, true, false><<<dim3(MB, 2), 256, 0, stream>>>(
        R0, g1_w2, g1_b2, scsh, scsh + 256, R1, nullptr, NNODES, 256, 256, 256);

    // ================= Layer 2 (256 -> 128 -> 128), REORDERED =================
    gemm128x128_kernel<false, false, false><<<dim3(MB, 1), 256, 0, stream>>>(
        R1, g2_w1, nullptr, nullptr, nullptr, R0, nullptr, NNODES, 256, 256, 128);
    gather_kernel<128, 4, 128><<<(NNODES * 32 + 255) / 256, 256, 0, stream>>>(R0, rowptr, adj, R1,
                                                                              g2_b1);
    hipMemsetAsync(stats, 0, 2 * 128 * sizeof(float), stream);
    bnstats_kernel<128><<<128, 256, 0, stream>>>(R1, stats);
    bnfinal_kernel<<<1, 128, 0, stream>>>(stats, g2_ga, g2_be, scsh, scsh + 128, 128, 1.0f / NNODES);
    gemm128x128_kernel<true, true, false><<<dim3(MB, 1), 256, 0, stream>>>(
        R1, g2_w2, g2_b2, scsh, scsh + 128, R0, nullptr, NNODES, 128, 128, 128);

    // ================= pool (segmented, no atomics) + FC head =================
    pool_seg_kernel<<<NGRAPHS, 128, 0, stream>>>(R0, gstart, g);

    gemm64_kernel<true><<<dim3(NGRAPHS / 64, 1024 / 64), 256, 0, stream>>>(g, fc0_w, fc0_b, gh,
                                                                           NGRAPHS, 128, 1024);
    gemm64_kernel<false><<<dim3(NGRAPHS / 64, 128 / 64), 256, 0, stream>>>(
        gh, fc1_w, fc1_b, (float*)d_out, NGRAPHS, 1024, 128);
}

// Round 9
// 1618.705 us; speedup vs baseline: 1.2649x; 1.2649x over previous
//
#include <hip/hip_runtime.h>

#define NNODES 100000
#define NEDGES 1600000
#define NGRAPHS 2048
#define BN_EPS 1e-5f

// ---------------- CSR build ----------------
__global__ __launch_bounds__(256) void deg_kernel(const int* __restrict__ dstA,
                                                  int* __restrict__ deg) {
    int e = blockIdx.x * 256 + threadIdx.x;
    if (e < NEDGES) atomicAdd(&deg[dstA[e]], 1);
}

// ---- 3-phase parallel exclusive scan of deg -> rowptr/cursor ----
__global__ __launch_bounds__(256) void scan1_kernel(const int* __restrict__ deg,
                                                    int* __restrict__ partials) {
    int b = blockIdx.x;
    int i = b * 256 + threadIdx.x;
    int v = (i < NNODES) ? deg[i] : 0;
    __shared__ int wsum[4];
#pragma unroll
    for (int off = 32; off; off >>= 1) v += __shfl_down(v, off);
    if ((threadIdx.x & 63) == 0) wsum[threadIdx.x >> 6] = v;
    __syncthreads();
    if (threadIdx.x == 0) partials[b] = wsum[0] + wsum[1] + wsum[2] + wsum[3];
}

__global__ __launch_bounds__(512) void scan2_kernel(int* __restrict__ partials, int nb) {
    __shared__ int s[512];
    int t = threadIdx.x;
    int v = (t < nb) ? partials[t] : 0;
    s[t] = v;
    __syncthreads();
    for (int off = 1; off < 512; off <<= 1) {
        int u = (t >= off) ? s[t - off] : 0;
        __syncthreads();
        s[t] += u;
        __syncthreads();
    }
    if (t < nb) partials[t] = s[t] - v;  // exclusive
}

__global__ __launch_bounds__(256) void scan3_kernel(const int* __restrict__ deg,
                                                    const int* __restrict__ partials,
                                                    int* __restrict__ rowptr,
                                                    int* __restrict__ cursor) {
    int b = blockIdx.x;
    int t = threadIdx.x;
    int i = b * 256 + t;
    __shared__ int s[256];
    int v = (i < NNODES) ? deg[i] : 0;
    s[t] = v;
    __syncthreads();
    for (int off = 1; off < 256; off <<= 1) {
        int u = (t >= off) ? s[t - off] : 0;
        __syncthreads();
        s[t] += u;
        __syncthreads();
    }
    if (i < NNODES) {
        int ex = partials[b] + s[t] - v;
        rowptr[i] = ex;
        cursor[i] = ex;
    }
    if (b == 0 && t == 0) rowptr[NNODES] = NEDGES;  // sum(deg) == NEDGES
}

__global__ __launch_bounds__(256) void fill_kernel(const int* __restrict__ srcA,
                                                   const int* __restrict__ dstA,
                                                   int* __restrict__ cursor,
                                                   int* __restrict__ adj) {
    int e = blockIdx.x * 256 + threadIdx.x;
    if (e < NEDGES) {
        int d = dstA[e];
        int loc = atomicAdd(&cursor[d], 1);
        adj[loc] = srcA[e];
    }
}

// ---- graph boundaries from sorted batch: gstart[g] = first node of graph g ----
__global__ __launch_bounds__(256) void gbound_kernel(const int* __restrict__ batch,
                                                     int* __restrict__ gstart) {
    int i = blockIdx.x * 256 + threadIdx.x;
    if (i >= NNODES) return;
    int b = batch[i];
    int bp = (i == 0) ? -1 : batch[i - 1];
    for (int g = bp + 1; g <= b; ++g) gstart[g] = i;
    if (i == NNODES - 1)
        for (int g = b + 1; g <= NGRAPHS; ++g) gstart[g] = NNODES;
}

// ------- gather aggregation: agg[n] = x[n] + sum_{s in adj[n]} x[s] (+bias) -------
template <int DIM, int CHUNK, int OSTRIDE>
__global__ __launch_bounds__(256) void gather_kernel(const float* __restrict__ x,
                                                     const int* __restrict__ rowptr,
                                                     const int* __restrict__ adj,
                                                     float* __restrict__ agg,
                                                     const float* __restrict__ bias) {
    constexpr int PE = DIM / CHUNK;
    int gid = blockIdx.x * 256 + threadIdx.x;
    if (gid >= NNODES * PE) return;
    int node = gid / PE;
    int c = gid - node * PE;
    const int beg = rowptr[node];
    const int end = rowptr[node + 1];
    if (CHUNK == 4) {
        const float4* xp = (const float4*)x;
        float4 acc = xp[(size_t)node * PE + c];
        for (int i = beg; i < end; ++i) {
            int s = adj[i];
            float4 v = xp[(size_t)s * PE + c];
            acc.x += v.x;
            acc.y += v.y;
            acc.z += v.z;
            acc.w += v.w;
        }
        if (bias) {
            float4 b = *(const float4*)&bias[c * 4];
            acc.x += b.x; acc.y += b.y; acc.z += b.z; acc.w += b.w;
        }
        *(float4*)&agg[(size_t)node * OSTRIDE + c * 4] = acc;
    } else {
        const float2* xp = (const float2*)x;
        float2 acc = xp[(size_t)node * PE + c];
        for (int i = beg; i < end; ++i) {
            int s = adj[i];
            float2 v = xp[(size_t)s * PE + c];
            acc.x += v.x;
            acc.y += v.y;
        }
        *(float2*)&agg[(size_t)node * OSTRIDE + c * 2] = acc;
    }
}

// ---------------- BN stats (standalone, used once for L2) ----------------
template <int N>
__global__ __launch_bounds__(256) void bnstats_kernel(const float* __restrict__ h,
                                                      float* __restrict__ sums) {
    constexpr int SHIFT = (N == 128) ? 7 : 8;
    int t = blockIdx.x * 256 + threadIdx.x;
    int col = t & (N - 1);
    int slice = t >> SHIFT;
    float s = 0.f, s2 = 0.f;
    for (int r = slice; r < NNODES; r += 256) {
        float v = h[(size_t)r * N + col];
        s += v;
        s2 += v * v;
    }
    atomicAdd(&sums[col], s);
    atomicAdd(&sums[N + col], s2);
}

__global__ void bnfinal_kernel(const float* __restrict__ sums, const float* __restrict__ gamma,
                               const float* __restrict__ beta, float* __restrict__ scale,
                               float* __restrict__ shift, int N, float invM) {
    int c = blockIdx.x * blockDim.x + threadIdx.x;
    if (c < N) {
        float mean = sums[c] * invM;
        float var = sums[N + c] * invM - mean * mean;
        float sc = gamma[c] * rsqrtf(var + BN_EPS);
        scale[c] = sc;
        shift[c] = beta[c] - mean * sc;
    }
}

__device__ __forceinline__ void fma44(float (&cc)[4][4], const float4& a, const float4& b) {
    cc[0][0] += a.x * b.x; cc[0][1] += a.x * b.y; cc[0][2] += a.x * b.z; cc[0][3] += a.x * b.w;
    cc[1][0] += a.y * b.x; cc[1][1] += a.y * b.y; cc[1][2] += a.y * b.z; cc[1][3] += a.y * b.w;
    cc[2][0] += a.z * b.x; cc[2][1] += a.z * b.y; cc[2][2] += a.z * b.z; cc[2][3] += a.z * b.w;
    cc[3][0] += a.w * b.x; cc[3][1] += a.w * b.y; cc[3][2] += a.w * b.z; cc[3][3] += a.w * b.w;
}

// ---------------- 128x128 tile fp32 GEMM, 8x8/thread (2x2 quadrants), prefetched ---------
// R8 post-mortem: __launch_bounds__(256,3) made the allocator target ~84 VGPR and spill
// the 64-reg accumulator to scratch (WRITE_SIZE 966MB, 3.8TB/s HBM). R4 proved this
// geometry fits at 132 VGPR when unconstrained. So: NO min-wave hint; keep the R5-proven
// next-kk value prefetch to hide LDS latency within-wave at 2-3 waves/SIMD.
template <bool BNRELU_A, bool RELU_OUT, bool FUSE_STATS>
__global__ __launch_bounds__(256) void gemm128x128_kernel(
    const float* __restrict__ A, const float* __restrict__ W, const float* __restrict__ bias,
    const float* __restrict__ scale, const float* __restrict__ shift, float* __restrict__ C,
    float* __restrict__ stats, int M, int K, int Kw, int N) {
    __shared__ __align__(16) float As[16][132];  // [k][m], 132 stride
    __shared__ __align__(16) float Bs[16][128];  // [k][n]
    __shared__ float sstat[256];                 // 128 sum + 128 sumsq
    const int tid = threadIdx.x;
    const int tx = tid & 15;
    const int ty = tid >> 4;
    const int m0 = blockIdx.x * 128;
    const int n0 = blockIdx.y * 128;

    if (FUSE_STATS) sstat[tid] = 0.f;  // synced by first k-loop barrier

    float c[2][2][4][4] = {};

    for (int k0 = 0; k0 < K; k0 += 16) {
        // ---- stage A tile (128 rows x 16 k) transposed into As[k][m] ----
#pragma unroll
        for (int i = 0; i < 2; ++i) {
            int lin4 = tid + i * 256;  // [0,512)
            int row = lin4 >> 2;       // 0..127
            int kq = lin4 & 3;         // k-quad
            int gm = m0 + row;
            float4 v = make_float4(0.f, 0.f, 0.f, 0.f);
            if (gm < M) v = *(const float4*)&A[(size_t)gm * K + k0 + kq * 4];
            if (BNRELU_A) {
                int gk = k0 + kq * 4;
                v.x = fmaxf(v.x * scale[gk + 0] + shift[gk + 0], 0.f);
                v.y = fmaxf(v.y * scale[gk + 1] + shift[gk + 1], 0.f);
                v.z = fmaxf(v.z * scale[gk + 2] + shift[gk + 2], 0.f);
                v.w = fmaxf(v.w * scale[gk + 3] + shift[gk + 3], 0.f);
            }
            As[kq * 4 + 0][row] = v.x;
            As[kq * 4 + 1][row] = v.y;
            As[kq * 4 + 2][row] = v.z;
            As[kq * 4 + 3][row] = v.w;
        }
        // ---- stage W tile (16 k x 128 n): 2 float4 per thread; guard by Kw ----
#pragma unroll
        for (int i = 0; i < 2; ++i) {
            int lin4 = tid + i * 256;  // [0,512)
            int kr = lin4 >> 5;        // 0..15
            int nq = lin4 & 31;        // 0..31
            int gk = k0 + kr;
            float4 v = make_float4(0.f, 0.f, 0.f, 0.f);
            if (gk < Kw) v = *(const float4*)&W[(size_t)gk * N + n0 + nq * 4];
            *(float4*)&Bs[kr][nq * 4] = v;
        }
        __syncthreads();
        // ---- inner product, next-kk value prefetch ----
        float4 a0 = *(const float4*)&As[0][ty * 4];
        float4 a1 = *(const float4*)&As[0][64 + ty * 4];
        float4 b0 = *(const float4*)&Bs[0][tx * 4];
        float4 b1 = *(const float4*)&Bs[0][64 + tx * 4];
#pragma unroll
        for (int kk = 0; kk < 16; ++kk) {
            float4 na0, na1, nb0, nb1;
            if (kk < 15) {
                na0 = *(const float4*)&As[kk + 1][ty * 4];
                na1 = *(const float4*)&As[kk + 1][64 + ty * 4];
                nb0 = *(const float4*)&Bs[kk + 1][tx * 4];
                nb1 = *(const float4*)&Bs[kk + 1][64 + tx * 4];
            }
            fma44(c[0][0], a0, b0);
            fma44(c[0][1], a0, b1);
            fma44(c[1][0], a1, b0);
            fma44(c[1][1], a1, b1);
            if (kk < 15) {
                a0 = na0;
                a1 = na1;
                b0 = nb0;
                b1 = nb1;
            }
        }
        __syncthreads();
    }

    // ---- epilogue: bias (+relu) store, optional fused column stats ----
    float s_sum[8] = {}, s_sq[8] = {};
    const bool hasb = (bias != nullptr);
    float4 bv[2] = {make_float4(0.f, 0.f, 0.f, 0.f), make_float4(0.f, 0.f, 0.f, 0.f)};
    if (hasb) {
        bv[0] = *(const float4*)&bias[n0 + tx * 4];
        bv[1] = *(const float4*)&bias[n0 + 64 + tx * 4];
    }
#pragma unroll
    for (int qa = 0; qa < 2; ++qa) {
#pragma unroll
        for (int i = 0; i < 4; ++i) {
            int gm = m0 + qa * 64 + ty * 4 + i;
            if (gm >= M) continue;
#pragma unroll
            for (int qb = 0; qb < 2; ++qb) {
                int gn = n0 + qb * 64 + tx * 4;
                float4 v;
                v.x = c[qa][qb][i][0] + bv[qb].x;
                v.y = c[qa][qb][i][1] + bv[qb].y;
                v.z = c[qa][qb][i][2] + bv[qb].z;
                v.w = c[qa][qb][i][3] + bv[qb].w;
                if (RELU_OUT) {
                    v.x = fmaxf(v.x, 0.f); v.y = fmaxf(v.y, 0.f);
                    v.z = fmaxf(v.z, 0.f); v.w = fmaxf(v.w, 0.f);
                }
                *(float4*)&C[(size_t)gm * N + gn] = v;
                if (FUSE_STATS) {
                    s_sum[qb * 4 + 0] += v.x; s_sq[qb * 4 + 0] += v.x * v.x;
                    s_sum[qb * 4 + 1] += v.y; s_sq[qb * 4 + 1] += v.y * v.y;
                    s_sum[qb * 4 + 2] += v.z; s_sq[qb * 4 + 2] += v.z * v.z;
                    s_sum[qb * 4 + 3] += v.w; s_sq[qb * 4 + 3] += v.w * v.w;
                }
            }
        }
    }
    if (FUSE_STATS) {
#pragma unroll
        for (int qb = 0; qb < 2; ++qb)
#pragma unroll
            for (int j = 0; j < 4; ++j) {
                int cl = qb * 64 + tx * 4 + j;
                atomicAdd(&sstat[cl], s_sum[qb * 4 + j]);
                atomicAdd(&sstat[128 + cl], s_sq[qb * 4 + j]);
            }
        __syncthreads();
        if (tid < 128) {
            atomicAdd(&stats[n0 + tid], sstat[tid]);
            atomicAdd(&stats[N + n0 + tid], sstat[128 + tid]);
        }
    }
}

// ---------------- 64x64 tile fp32 GEMM (fc0/fc1 head) ----------------
template <bool RELU_OUT>
__global__ __launch_bounds__(256) void gemm64_kernel(const float* __restrict__ A,
                                                     const float* __restrict__ W,
                                                     const float* __restrict__ bias,
                                                     float* __restrict__ C, int M, int K, int N) {
    __shared__ __align__(16) float As[16][68];
    __shared__ __align__(16) float Bs[16][64];
    const int tid = threadIdx.x;
    const int tx = tid & 15;
    const int ty = tid >> 4;
    const int m0 = blockIdx.x * 64;
    const int n0 = blockIdx.y * 64;

    float c[4][4] = {};

    for (int k0 = 0; k0 < K; k0 += 16) {
#pragma unroll
        for (int i = 0; i < 4; ++i) {
            int lin = tid + i * 256;
            int m = lin >> 4;
            int k = lin & 15;
            int gm = m0 + m;
            int gk = k0 + k;
            float v = 0.f;
            if (gm < M && gk < K) v = A[(size_t)gm * K + gk];
            As[k][m] = v;
        }
#pragma unroll
        for (int i = 0; i < 4; ++i) {
            int lin = tid + i * 256;
            int k = lin >> 6;
            int n = lin & 63;
            int gk = k0 + k;
            float v = 0.f;
            if (gk < K) v = W[(size_t)gk * N + n0 + n];
            Bs[k][n] = v;
        }
        __syncthreads();
#pragma unroll
        for (int kk = 0; kk < 16; ++kk) {
            float4 a = *(const float4*)&As[kk][ty * 4];
            float4 b = *(const float4*)&Bs[kk][tx * 4];
            c[0][0] += a.x * b.x; c[0][1] += a.x * b.y; c[0][2] += a.x * b.z; c[0][3] += a.x * b.w;
            c[1][0] += a.y * b.x; c[1][1] += a.y * b.y; c[1][2] += a.y * b.z; c[1][3] += a.y * b.w;
            c[2][0] += a.z * b.x; c[2][1] += a.z * b.y; c[2][2] += a.z * b.z; c[2][3] += a.z * b.w;
            c[3][0] += a.w * b.x; c[3][1] += a.w * b.y; c[3][2] += a.w * b.z; c[3][3] += a.w * b.w;
        }
        __syncthreads();
    }

#pragma unroll
    for (int i = 0; i < 4; ++i) {
        int gm = m0 + ty * 4 + i;
        if (gm >= M) continue;
#pragma unroll
        for (int j = 0; j < 4; ++j) {
            int gn = n0 + tx * 4 + j;
            float v = c[i][j] + bias[gn];
            if (RELU_OUT) v = fmaxf(v, 0.f);
            C[(size_t)gm * N + gn] = v;
        }
    }
}

// ---- segmented pool over sorted batch ----
__global__ __launch_bounds__(128) void pool_seg_kernel(const float* __restrict__ h,
                                                       const int* __restrict__ gstart,
                                                       float* __restrict__ g) {
    int gr = blockIdx.x;
    int t = threadIdx.x;  // column 0..127
    int beg = gstart[gr];
    int end = gstart[gr + 1];
    float acc = 0.f;
    for (int r = beg; r < end; ++r) acc += h[(size_t)r * 128 + t];
    g[(size_t)gr * 128 + t] = acc;
}

extern "C" void kernel_launch(void* const* d_in, const int* in_sizes, int n_in, void* d_out,
                              int out_size, void* d_ws, size_t ws_size, hipStream_t stream) {
    const float* x = (const float*)d_in[0];
    const int* ei = (const int*)d_in[1];
    const int* batch = (const int*)d_in[2];
    const int* srcA = ei;
    const int* dstA = ei + NEDGES;

    const float* g0_w1 = (const float*)d_in[3];
    const float* g0_b1 = (const float*)d_in[4];
    const float* g0_ga = (const float*)d_in[5];
    const float* g0_be = (const float*)d_in[6];
    const float* g0_w2 = (const float*)d_in[7];
    const float* g0_b2 = (const float*)d_in[8];
    const float* g1_w1 = (const float*)d_in[9];
    const float* g1_b1 = (const float*)d_in[10];
    const float* g1_ga = (const float*)d_in[11];
    const float* g1_be = (const float*)d_in[12];
    const float* g1_w2 = (const float*)d_in[13];
    const float* g1_b2 = (const float*)d_in[14];
    const float* g2_w1 = (const float*)d_in[15];
    const float* g2_b1 = (const float*)d_in[16];
    const float* g2_ga = (const float*)d_in[17];
    const float* g2_be = (const float*)d_in[18];
    const float* g2_w2 = (const float*)d_in[19];
    const float* g2_b2 = (const float*)d_in[20];
    const float* fc0_w = (const float*)d_in[21];
    const float* fc0_b = (const float*)d_in[22];
    const float* fc1_w = (const float*)d_in[23];
    const float* fc1_b = (const float*)d_in[24];

    // --- workspace layout (~222 MB) ---
    float* ws = (float*)d_ws;
    const size_t BUF = (size_t)NNODES * 256;
    float* R0 = ws;
    float* R1 = R0 + BUF;
    float* stats = R1 + BUF;                         // 2*256
    float* scsh = stats + 512;                       // 2*256 (scale, shift)
    float* g = scsh + 512;                           // 2048*128 pooled
    float* gh = g + (size_t)NGRAPHS * 128;           // 2048*1024 fc hidden
    int* deg = (int*)(gh + (size_t)NGRAPHS * 1024);  // NNODES
    int* rowptr = deg + NNODES;                      // NNODES+1
    int* cursor = rowptr + NNODES + 4;               // NNODES
    int* adj = cursor + NNODES;                      // NEDGES
    int* partials = adj + NEDGES;                    // 391
    int* gstart = partials + 512;                    // NGRAPHS+1

    const int MB = (NNODES + 127) / 128;  // 782 row-blocks
    const int NB = (NNODES + 255) / 256;  // 391 scan blocks

    // --- build CSR + graph bounds once ---
    hipMemsetAsync(deg, 0, NNODES * sizeof(int), stream);
    deg_kernel<<<(NEDGES + 255) / 256, 256, 0, stream>>>(dstA, deg);
    scan1_kernel<<<NB, 256, 0, stream>>>(deg, partials);
    scan2_kernel<<<1, 512, 0, stream>>>(partials, NB);
    scan3_kernel<<<NB, 256, 0, stream>>>(deg, partials, rowptr, cursor);
    fill_kernel<<<(NEDGES + 255) / 256, 256, 0, stream>>>(srcA, dstA, cursor, adj);
    gbound_kernel<<<NB, 256, 0, stream>>>(batch, gstart);

    // ================= Layer 0 (66 -> 128 -> 128) =================
    gather_kernel<66, 2, 68><<<(NNODES * 33 + 255) / 256, 256, 0, stream>>>(x, rowptr, adj, R0,
                                                                            nullptr);
    hipMemsetAsync(stats, 0, 2 * 128 * sizeof(float), stream);
    gemm128x128_kernel<false, false, true><<<dim3(MB, 1), 256, 0, stream>>>(
        R0, g0_w1, g0_b1, nullptr, nullptr, R1, stats, NNODES, 68, 66, 128);
    bnfinal_kernel<<<1, 128, 0, stream>>>(stats, g0_ga, g0_be, scsh, scsh + 128, 128, 1.0f / NNODES);
    gemm128x128_kernel<true, true, false><<<dim3(MB, 1), 256, 0, stream>>>(
        R1, g0_w2, g0_b2, scsh, scsh + 128, R0, nullptr, NNODES, 128, 128, 128);

    // ================= Layer 1 (128 -> 256 -> 256) =================
    gather_kernel<128, 4, 128><<<(NNODES * 32 + 255) / 256, 256, 0, stream>>>(R0, rowptr, adj, R1,
                                                                              nullptr);
    hipMemsetAsync(stats, 0, 2 * 256 * sizeof(float), stream);
    gemm128x128_kernel<false, false, true><<<dim3(MB, 2), 256, 0, stream>>>(
        R1, g1_w1, g1_b1, nullptr, nullptr, R0, stats, NNODES, 128, 128, 256);
    bnfinal_kernel<<<1, 256, 0, stream>>>(stats, g1_ga, g1_be, scsh, scsh + 256, 256, 1.0f / NNODES);
    gemm128x128_kernel<true, true, false><<<dim3(MB, 2), 256, 0, stream>>>(
        R0, g1_w2, g1_b2, scsh, scsh + 256, R1, nullptr, NNODES, 256, 256, 256);

    // ================= Layer 2 (256 -> 128 -> 128), REORDERED =================
    gemm128x128_kernel<false, false, false><<<dim3(MB, 1), 256, 0, stream>>>(
        R1, g2_w1, nullptr, nullptr, nullptr, R0, nullptr, NNODES, 256, 256, 128);
    gather_kernel<128, 4, 128><<<(NNODES * 32 + 255) / 256, 256, 0, stream>>>(R0, rowptr, adj, R1,
                                                                              g2_b1);
    hipMemsetAsync(stats, 0, 2 * 128 * sizeof(float), stream);
    bnstats_kernel<128><<<128, 256, 0, stream>>>(R1, stats);
    bnfinal_kernel<<<1, 128, 0, stream>>>(stats, g2_ga, g2_be, scsh, scsh + 128, 128, 1.0f / NNODES);
    gemm128x128_kernel<true, true, false><<<dim3(MB, 1), 256, 0, stream>>>(
        R1, g2_w2, g2_b2, scsh, scsh + 128, R0, nullptr, NNODES, 128, 128, 128);

    // ================= pool (segmented, no atomics) + FC head =================
    pool_seg_kernel<<<NGRAPHS, 128, 0, stream>>>(R0, gstart, g);

    gemm64_kernel<true><<<dim3(NGRAPHS / 64, 1024 / 64), 256, 0, stream>>>(g, fc0_w, fc0_b, gh,
                                                                           NGRAPHS, 128, 1024);
    gemm64_kernel<false><<<dim3(NGRAPHS / 64, 128 / 64), 256, 0, stream>>>(
        gh, fc1_w, fc1_b, (float*)d_out, NGRAPHS, 1024, 128);
}

// Round 10
// 1615.171 us; speedup vs baseline: 1.2676x; 1.0022x over previous
//
#include <hip/hip_runtime.h>

#define NNODES 100000
#define NEDGES 1600000
#define NGRAPHS 2048
#define BN_EPS 1e-5f

// ---------------- CSR build ----------------
__global__ __launch_bounds__(256) void deg_kernel(const int* __restrict__ dstA,
                                                  int* __restrict__ deg) {
    int e = blockIdx.x * 256 + threadIdx.x;
    if (e < NEDGES) atomicAdd(&deg[dstA[e]], 1);
}

// ---- 3-phase parallel exclusive scan of deg -> rowptr/cursor ----
__global__ __launch_bounds__(256) void scan1_kernel(const int* __restrict__ deg,
                                                    int* __restrict__ partials) {
    int b = blockIdx.x;
    int i = b * 256 + threadIdx.x;
    int v = (i < NNODES) ? deg[i] : 0;
    __shared__ int wsum[4];
#pragma unroll
    for (int off = 32; off; off >>= 1) v += __shfl_down(v, off);
    if ((threadIdx.x & 63) == 0) wsum[threadIdx.x >> 6] = v;
    __syncthreads();
    if (threadIdx.x == 0) partials[b] = wsum[0] + wsum[1] + wsum[2] + wsum[3];
}

__global__ __launch_bounds__(512) void scan2_kernel(int* __restrict__ partials, int nb) {
    __shared__ int s[512];
    int t = threadIdx.x;
    int v = (t < nb) ? partials[t] : 0;
    s[t] = v;
    __syncthreads();
    for (int off = 1; off < 512; off <<= 1) {
        int u = (t >= off) ? s[t - off] : 0;
        __syncthreads();
        s[t] += u;
        __syncthreads();
    }
    if (t < nb) partials[t] = s[t] - v;  // exclusive
}

// phase 3 + graph-boundary detection (merged gbound: saves a launch)
__global__ __launch_bounds__(256) void scan3_kernel(const int* __restrict__ deg,
                                                    const int* __restrict__ partials,
                                                    int* __restrict__ rowptr,
                                                    int* __restrict__ cursor,
                                                    const int* __restrict__ batch,
                                                    int* __restrict__ gstart) {
    int b = blockIdx.x;
    int t = threadIdx.x;
    int i = b * 256 + t;
    __shared__ int s[256];
    int v = (i < NNODES) ? deg[i] : 0;
    s[t] = v;
    __syncthreads();
    for (int off = 1; off < 256; off <<= 1) {
        int u = (t >= off) ? s[t - off] : 0;
        __syncthreads();
        s[t] += u;
        __syncthreads();
    }
    if (i < NNODES) {
        int ex = partials[b] + s[t] - v;
        rowptr[i] = ex;
        cursor[i] = ex;
        // graph boundaries from sorted batch
        int bb = batch[i];
        int bp = (i == 0) ? -1 : batch[i - 1];
        for (int g = bp + 1; g <= bb; ++g) gstart[g] = i;
        if (i == NNODES - 1)
            for (int g = bb + 1; g <= NGRAPHS; ++g) gstart[g] = NNODES;
    }
    if (b == 0 && t == 0) rowptr[NNODES] = NEDGES;  // sum(deg) == NEDGES
}

__global__ __launch_bounds__(256) void fill_kernel(const int* __restrict__ srcA,
                                                   const int* __restrict__ dstA,
                                                   int* __restrict__ cursor,
                                                   int* __restrict__ adj) {
    int e = blockIdx.x * 256 + threadIdx.x;
    if (e < NEDGES) {
        int d = dstA[e];
        int loc = atomicAdd(&cursor[d], 1);
        adj[loc] = srcA[e];
    }
}

// ------- gather aggregation: agg[n] = x[n] + sum_{s in adj[n]} x[s] (+bias) -------
template <int DIM, int CHUNK, int OSTRIDE>
__global__ __launch_bounds__(256) void gather_kernel(const float* __restrict__ x,
                                                     const int* __restrict__ rowptr,
                                                     const int* __restrict__ adj,
                                                     float* __restrict__ agg,
                                                     const float* __restrict__ bias) {
    constexpr int PE = DIM / CHUNK;
    int gid = blockIdx.x * 256 + threadIdx.x;
    if (gid >= NNODES * PE) return;
    int node = gid / PE;
    int c = gid - node * PE;
    const int beg = rowptr[node];
    const int end = rowptr[node + 1];
    if (CHUNK == 4) {
        const float4* xp = (const float4*)x;
        float4 acc = xp[(size_t)node * PE + c];
        for (int i = beg; i < end; ++i) {
            int s = adj[i];
            float4 v = xp[(size_t)s * PE + c];
            acc.x += v.x;
            acc.y += v.y;
            acc.z += v.z;
            acc.w += v.w;
        }
        if (bias) {
            float4 b = *(const float4*)&bias[c * 4];
            acc.x += b.x; acc.y += b.y; acc.z += b.z; acc.w += b.w;
        }
        *(float4*)&agg[(size_t)node * OSTRIDE + c * 4] = acc;
    } else {
        const float2* xp = (const float2*)x;
        float2 acc = xp[(size_t)node * PE + c];
        for (int i = beg; i < end; ++i) {
            int s = adj[i];
            float2 v = xp[(size_t)s * PE + c];
            acc.x += v.x;
            acc.y += v.y;
        }
        *(float2*)&agg[(size_t)node * OSTRIDE + c * 2] = acc;
    }
}

// ---------------- BN stats (standalone, used once for L2) ----------------
// Fixed layout: sum at sums[col], sumsq at sums[256+col].
template <int N>
__global__ __launch_bounds__(256) void bnstats_kernel(const float* __restrict__ h,
                                                      float* __restrict__ sums) {
    constexpr int SHIFT = (N == 128) ? 7 : 8;
    int t = blockIdx.x * 256 + threadIdx.x;
    int col = t & (N - 1);
    int slice = t >> SHIFT;
    float s = 0.f, s2 = 0.f;
    for (int r = slice; r < NNODES; r += 256) {
        float v = h[(size_t)r * N + col];
        s += v;
        s2 += v * v;
    }
    atomicAdd(&sums[col], s);
    atomicAdd(&sums[256 + col], s2);
}

// reads sums (sum@c, sumsq@256+c), writes scale@c / shift@256+c, then RE-ZEROES sums
// (so no per-layer memset is needed; one initial memset per call).
__global__ void bnfinal_kernel(float* __restrict__ sums, const float* __restrict__ gamma,
                               const float* __restrict__ beta, float* __restrict__ scsh, int N,
                               float invM) {
    int c = threadIdx.x;  // 256 threads always
    if (c < N) {
        float mean = sums[c] * invM;
        float var = sums[256 + c] * invM - mean * mean;
        float sc = gamma[c] * rsqrtf(var + BN_EPS);
        scsh[c] = sc;
        scsh[256 + c] = beta[c] - mean * sc;
    }
    sums[c] = 0.f;
    sums[256 + c] = 0.f;
}

__device__ __forceinline__ void fma44(float (&cc)[4][4], const float4& a, const float4& b) {
    cc[0][0] += a.x * b.x; cc[0][1] += a.x * b.y; cc[0][2] += a.x * b.z; cc[0][3] += a.x * b.w;
    cc[1][0] += a.y * b.x; cc[1][1] += a.y * b.y; cc[1][2] += a.y * b.z; cc[1][3] += a.y * b.w;
    cc[2][0] += a.z * b.x; cc[2][1] += a.z * b.y; cc[2][2] += a.z * b.z; cc[2][3] += a.z * b.w;
    cc[3][0] += a.w * b.x; cc[3][1] += a.w * b.y; cc[3][2] += a.w * b.z; cc[3][3] += a.w * b.w;
}

// ---------------- 128x64 tile fp32 GEMM, 8x4/thread (R7-proven, at LDS-throughput floor) ----
// R8/R9 post-mortem: 8x8 (64-acc) variants miss their LDS model by ~76% (220us vs 125us
// predicted) with or without __launch_bounds__ hints; 8x4 sits exactly on its 2.25x-FMA
// LDS floor (191us). Keep 8x4. Stats layout: sum@stats[col], sumsq@stats[256+col].
// scale = scsh[k], shift = scsh[256+k].
template <bool BNRELU_A, bool RELU_OUT, bool FUSE_STATS>
__global__ __launch_bounds__(256) void gemm128x64_kernel(
    const float* __restrict__ A, const float* __restrict__ W, const float* __restrict__ bias,
    const float* __restrict__ scsh, float* __restrict__ C, float* __restrict__ stats, int M,
    int K, int Kw, int N) {
    __shared__ __align__(16) float As[16][132];
    __shared__ __align__(16) float Bs[16][64];
    __shared__ float sstat[128];
    const int tid = threadIdx.x;
    const int tx = tid & 15;
    const int ty = tid >> 4;
    const int m0 = blockIdx.x * 128;
    const int n0 = blockIdx.y * 64;

    if (FUSE_STATS && tid < 128) sstat[tid] = 0.f;

    float c[2][4][4] = {};

    for (int k0 = 0; k0 < K; k0 += 16) {
#pragma unroll
        for (int i = 0; i < 2; ++i) {
            int lin4 = tid + i * 256;
            int row = lin4 >> 2;
            int kq = lin4 & 3;
            int gm = m0 + row;
            float4 v = make_float4(0.f, 0.f, 0.f, 0.f);
            if (gm < M) v = *(const float4*)&A[(size_t)gm * K + k0 + kq * 4];
            if (BNRELU_A) {
                int gk = k0 + kq * 4;
                v.x = fmaxf(v.x * scsh[gk + 0] + scsh[256 + gk + 0], 0.f);
                v.y = fmaxf(v.y * scsh[gk + 1] + scsh[256 + gk + 1], 0.f);
                v.z = fmaxf(v.z * scsh[gk + 2] + scsh[256 + gk + 2], 0.f);
                v.w = fmaxf(v.w * scsh[gk + 3] + scsh[256 + gk + 3], 0.f);
            }
            As[kq * 4 + 0][row] = v.x;
            As[kq * 4 + 1][row] = v.y;
            As[kq * 4 + 2][row] = v.z;
            As[kq * 4 + 3][row] = v.w;
        }
        {
            int kr = tid >> 4;
            int nq = tid & 15;
            int gk = k0 + kr;
            float4 v = make_float4(0.f, 0.f, 0.f, 0.f);
            if (gk < Kw) v = *(const float4*)&W[(size_t)gk * N + n0 + nq * 4];
            *(float4*)&Bs[kr][nq * 4] = v;
        }
        __syncthreads();
        float4 a0 = *(const float4*)&As[0][ty * 4];
        float4 a1 = *(const float4*)&As[0][64 + ty * 4];
        float4 b = *(const float4*)&Bs[0][tx * 4];
#pragma unroll
        for (int kk = 0; kk < 16; ++kk) {
            float4 na0, na1, nb;
            if (kk < 15) {
                na0 = *(const float4*)&As[kk + 1][ty * 4];
                na1 = *(const float4*)&As[kk + 1][64 + ty * 4];
                nb = *(const float4*)&Bs[kk + 1][tx * 4];
            }
            fma44(c[0], a0, b);
            fma44(c[1], a1, b);
            if (kk < 15) {
                a0 = na0;
                a1 = na1;
                b = nb;
            }
        }
        __syncthreads();
    }

    float s_sum[4] = {}, s_sq[4] = {};
    const bool hasb = (bias != nullptr);
    const int gn = n0 + tx * 4;
    float4 bv = make_float4(0.f, 0.f, 0.f, 0.f);
    if (hasb) bv = *(const float4*)&bias[gn];
#pragma unroll
    for (int qa = 0; qa < 2; ++qa) {
#pragma unroll
        for (int i = 0; i < 4; ++i) {
            int gm = m0 + qa * 64 + ty * 4 + i;
            if (gm >= M) continue;
            float4 v;
            v.x = c[qa][i][0] + bv.x;
            v.y = c[qa][i][1] + bv.y;
            v.z = c[qa][i][2] + bv.z;
            v.w = c[qa][i][3] + bv.w;
            if (RELU_OUT) {
                v.x = fmaxf(v.x, 0.f); v.y = fmaxf(v.y, 0.f);
                v.z = fmaxf(v.z, 0.f); v.w = fmaxf(v.w, 0.f);
            }
            *(float4*)&C[(size_t)gm * N + gn] = v;
            if (FUSE_STATS) {
                s_sum[0] += v.x; s_sq[0] += v.x * v.x;
                s_sum[1] += v.y; s_sq[1] += v.y * v.y;
                s_sum[2] += v.z; s_sq[2] += v.z * v.z;
                s_sum[3] += v.w; s_sq[3] += v.w * v.w;
            }
        }
    }
    if (FUSE_STATS) {
#pragma unroll
        for (int j = 0; j < 4; ++j) {
            int cl = tx * 4 + j;
            atomicAdd(&sstat[cl], s_sum[j]);
            atomicAdd(&sstat[64 + cl], s_sq[j]);
        }
        __syncthreads();
        if (tid < 64) {
            atomicAdd(&stats[n0 + tid], sstat[tid]);
            atomicAdd(&stats[256 + n0 + tid], sstat[64 + tid]);
        }
    }
}

// ---------------- 64x64 tile fp32 GEMM (fc0/fc1 head) ----------------
template <bool RELU_OUT>
__global__ __launch_bounds__(256) void gemm64_kernel(const float* __restrict__ A,
                                                     const float* __restrict__ W,
                                                     const float* __restrict__ bias,
                                                     float* __restrict__ C, int M, int K, int N) {
    __shared__ __align__(16) float As[16][68];
    __shared__ __align__(16) float Bs[16][64];
    const int tid = threadIdx.x;
    const int tx = tid & 15;
    const int ty = tid >> 4;
    const int m0 = blockIdx.x * 64;
    const int n0 = blockIdx.y * 64;

    float c[4][4] = {};

    for (int k0 = 0; k0 < K; k0 += 16) {
#pragma unroll
        for (int i = 0; i < 4; ++i) {
            int lin = tid + i * 256;
            int m = lin >> 4;
            int k = lin & 15;
            int gm = m0 + m;
            int gk = k0 + k;
            float v = 0.f;
            if (gm < M && gk < K) v = A[(size_t)gm * K + gk];
            As[k][m] = v;
        }
#pragma unroll
        for (int i = 0; i < 4; ++i) {
            int lin = tid + i * 256;
            int k = lin >> 6;
            int n = lin & 63;
            int gk = k0 + k;
            float v = 0.f;
            if (gk < K) v = W[(size_t)gk * N + n0 + n];
            Bs[k][n] = v;
        }
        __syncthreads();
#pragma unroll
        for (int kk = 0; kk < 16; ++kk) {
            float4 a = *(const float4*)&As[kk][ty * 4];
            float4 b = *(const float4*)&Bs[kk][tx * 4];
            c[0][0] += a.x * b.x; c[0][1] += a.x * b.y; c[0][2] += a.x * b.z; c[0][3] += a.x * b.w;
            c[1][0] += a.y * b.x; c[1][1] += a.y * b.y; c[1][2] += a.y * b.z; c[1][3] += a.y * b.w;
            c[2][0] += a.z * b.x; c[2][1] += a.z * b.y; c[2][2] += a.z * b.z; c[2][3] += a.z * b.w;
            c[3][0] += a.w * b.x; c[3][1] += a.w * b.y; c[3][2] += a.w * b.z; c[3][3] += a.w * b.w;
        }
        __syncthreads();
    }

#pragma unroll
    for (int i = 0; i < 4; ++i) {
        int gm = m0 + ty * 4 + i;
        if (gm >= M) continue;
#pragma unroll
        for (int j = 0; j < 4; ++j) {
            int gn = n0 + tx * 4 + j;
            float v = c[i][j] + bias[gn];
            if (RELU_OUT) v = fmaxf(v, 0.f);
            C[(size_t)gm * N + gn] = v;
        }
    }
}

// ---- segmented pool over sorted batch ----
__global__ __launch_bounds__(128) void pool_seg_kernel(const float* __restrict__ h,
                                                       const int* __restrict__ gstart,
                                                       float* __restrict__ g) {
    int gr = blockIdx.x;
    int t = threadIdx.x;  // column 0..127
    int beg = gstart[gr];
    int end = gstart[gr + 1];
    float acc = 0.f;
    for (int r = beg; r < end; ++r) acc += h[(size_t)r * 128 + t];
    g[(size_t)gr * 128 + t] = acc;
}

extern "C" void kernel_launch(void* const* d_in, const int* in_sizes, int n_in, void* d_out,
                              int out_size, void* d_ws, size_t ws_size, hipStream_t stream) {
    const float* x = (const float*)d_in[0];
    const int* ei = (const int*)d_in[1];
    const int* batch = (const int*)d_in[2];
    const int* srcA = ei;
    const int* dstA = ei + NEDGES;

    const float* g0_w1 = (const float*)d_in[3];
    const float* g0_b1 = (const float*)d_in[4];
    const float* g0_ga = (const float*)d_in[5];
    const float* g0_be = (const float*)d_in[6];
    const float* g0_w2 = (const float*)d_in[7];
    const float* g0_b2 = (const float*)d_in[8];
    const float* g1_w1 = (const float*)d_in[9];
    const float* g1_b1 = (const float*)d_in[10];
    const float* g1_ga = (const float*)d_in[11];
    const float* g1_be = (const float*)d_in[12];
    const float* g1_w2 = (const float*)d_in[13];
    const float* g1_b2 = (const float*)d_in[14];
    const float* g2_w1 = (const float*)d_in[15];
    const float* g2_b1 = (const float*)d_in[16];
    const float* g2_ga = (const float*)d_in[17];
    const float* g2_be = (const float*)d_in[18];
    const float* g2_w2 = (const float*)d_in[19];
    const float* g2_b2 = (const float*)d_in[20];
    const float* fc0_w = (const float*)d_in[21];
    const float* fc0_b = (const float*)d_in[22];
    const float* fc1_w = (const float*)d_in[23];
    const float* fc1_b = (const float*)d_in[24];

    // --- workspace layout (~222 MB) ---
    float* ws = (float*)d_ws;
    const size_t BUF = (size_t)NNODES * 256;
    float* R0 = ws;
    float* R1 = R0 + BUF;
    float* stats = R1 + BUF;                         // 512 (sum@0..256, sumsq@256..512)
    float* scsh = stats + 512;                       // 512 (scale@0..256, shift@256..512)
    float* g = scsh + 512;                           // 2048*128 pooled
    float* gh = g + (size_t)NGRAPHS * 128;           // 2048*1024 fc hidden
    int* deg = (int*)(gh + (size_t)NGRAPHS * 1024);  // NNODES
    int* rowptr = deg + NNODES;                      // NNODES+1
    int* cursor = rowptr + NNODES + 4;               // NNODES
    int* adj = cursor + NNODES;                      // NEDGES
    int* partials = adj + NEDGES;                    // 391
    int* gstart = partials + 512;                    // NGRAPHS+1

    const int MB = (NNODES + 127) / 128;  // 782 row-blocks
    const int NB = (NNODES + 255) / 256;  // 391 scan blocks

    // --- build CSR + graph bounds once ---
    hipMemsetAsync(deg, 0, NNODES * sizeof(int), stream);
    hipMemsetAsync(stats, 0, 512 * sizeof(float), stream);  // bnfinal re-zeroes thereafter
    deg_kernel<<<(NEDGES + 255) / 256, 256, 0, stream>>>(dstA, deg);
    scan1_kernel<<<NB, 256, 0, stream>>>(deg, partials);
    scan2_kernel<<<1, 512, 0, stream>>>(partials, NB);
    scan3_kernel<<<NB, 256, 0, stream>>>(deg, partials, rowptr, cursor, batch, gstart);
    fill_kernel<<<(NEDGES + 255) / 256, 256, 0, stream>>>(srcA, dstA, cursor, adj);

    // ================= Layer 0 (66 -> 128 -> 128) =================
    gather_kernel<66, 2, 68><<<(NNODES * 33 + 255) / 256, 256, 0, stream>>>(x, rowptr, adj, R0,
                                                                            nullptr);
    gemm128x64_kernel<false, false, true><<<dim3(MB, 2), 256, 0, stream>>>(
        R0, g0_w1, g0_b1, nullptr, R1, stats, NNODES, 68, 66, 128);
    bnfinal_kernel<<<1, 256, 0, stream>>>(stats, g0_ga, g0_be, scsh, 128, 1.0f / NNODES);
    gemm128x64_kernel<true, true, false><<<dim3(MB, 2), 256, 0, stream>>>(
        R1, g0_w2, g0_b2, scsh, R0, nullptr, NNODES, 128, 128, 128);

    // ================= Layer 1 (128 -> 256 -> 256) =================
    // Big GEMMs split into N-halves: equal total work, and surfaces tier-2 kernels in top-5.
    gather_kernel<128, 4, 128><<<(NNODES * 32 + 255) / 256, 256, 0, stream>>>(R0, rowptr, adj, R1,
                                                                              nullptr);
    gemm128x64_kernel<false, false, true><<<dim3(MB, 2), 256, 0, stream>>>(
        R1, g1_w1, g1_b1, nullptr, R0, stats, NNODES, 128, 128, 256);
    gemm128x64_kernel<false, false, true><<<dim3(MB, 2), 256, 0, stream>>>(
        R1, g1_w1 + 128, g1_b1 + 128, nullptr, R0 + 128, stats + 128, NNODES, 128, 128, 256);
    bnfinal_kernel<<<1, 256, 0, stream>>>(stats, g1_ga, g1_be, scsh, 256, 1.0f / NNODES);
    gemm128x64_kernel<true, true, false><<<dim3(MB, 2), 256, 0, stream>>>(
        R0, g1_w2, g1_b2, scsh, R1, nullptr, NNODES, 256, 256, 256);
    gemm128x64_kernel<true, true, false><<<dim3(MB, 2), 256, 0, stream>>>(
        R0, g1_w2 + 128, g1_b2 + 128, scsh, R1 + 128, nullptr, NNODES, 256, 256, 256);

    // ================= Layer 2 (256 -> 128 -> 128), REORDERED =================
    gemm128x64_kernel<false, false, false><<<dim3(MB, 2), 256, 0, stream>>>(
        R1, g2_w1, nullptr, nullptr, R0, nullptr, NNODES, 256, 256, 128);
    gather_kernel<128, 4, 128><<<(NNODES * 32 + 255) / 256, 256, 0, stream>>>(R0, rowptr, adj, R1,
                                                                              g2_b1);
    bnstats_kernel<128><<<128, 256, 0, stream>>>(R1, stats);
    bnfinal_kernel<<<1, 256, 0, stream>>>(stats, g2_ga, g2_be, scsh, 128, 1.0f / NNODES);
    gemm128x64_kernel<true, true, false><<<dim3(MB, 2), 256, 0, stream>>>(
        R1, g2_w2, g2_b2, scsh, R0, nullptr, NNODES, 128, 128, 128);

    // ================= pool (segmented, no atomics) + FC head =================
    pool_seg_kernel<<<NGRAPHS, 128, 0, stream>>>(R0, gstart, g);

    gemm64_kernel<true><<<dim3(NGRAPHS / 64, 1024 / 64), 256, 0, stream>>>(g, fc0_w, fc0_b, gh,
                                                                           NGRAPHS, 128, 1024);
    gemm64_kernel<false><<<dim3(NGRAPHS / 64, 128 / 64), 256, 0, stream>>>(
        gh, fc1_w, fc1_b, (float*)d_out, NGRAPHS, 1024, 128);
}

// Round 11
// 1545.488 us; speedup vs baseline: 1.3248x; 1.0451x over previous
//
#include <hip/hip_runtime.h>

#define NNODES 100000
#define NEDGES 1600000
#define NGRAPHS 2048
#define BN_EPS 1e-5f

// ---------------- CSR build ----------------
__global__ __launch_bounds__(256) void deg_kernel(const int* __restrict__ dstA,
                                                  int* __restrict__ deg) {
    int e = blockIdx.x * 256 + threadIdx.x;
    if (e < NEDGES) atomicAdd(&deg[dstA[e]], 1);
}

// ---- 3-phase parallel exclusive scan of deg -> rowptr/cursor ----
__global__ __launch_bounds__(256) void scan1_kernel(const int* __restrict__ deg,
                                                    int* __restrict__ partials) {
    int b = blockIdx.x;
    int i = b * 256 + threadIdx.x;
    int v = (i < NNODES) ? deg[i] : 0;
    __shared__ int wsum[4];
#pragma unroll
    for (int off = 32; off; off >>= 1) v += __shfl_down(v, off);
    if ((threadIdx.x & 63) == 0) wsum[threadIdx.x >> 6] = v;
    __syncthreads();
    if (threadIdx.x == 0) partials[b] = wsum[0] + wsum[1] + wsum[2] + wsum[3];
}

__global__ __launch_bounds__(512) void scan2_kernel(int* __restrict__ partials, int nb) {
    __shared__ int s[512];
    int t = threadIdx.x;
    int v = (t < nb) ? partials[t] : 0;
    s[t] = v;
    __syncthreads();
    for (int off = 1; off < 512; off <<= 1) {
        int u = (t >= off) ? s[t - off] : 0;
        __syncthreads();
        s[t] += u;
        __syncthreads();
    }
    if (t < nb) partials[t] = s[t] - v;  // exclusive
}

// phase 3 + graph-boundary detection (merged gbound)
__global__ __launch_bounds__(256) void scan3_kernel(const int* __restrict__ deg,
                                                    const int* __restrict__ partials,
                                                    int* __restrict__ rowptr,
                                                    int* __restrict__ cursor,
                                                    const int* __restrict__ batch,
                                                    int* __restrict__ gstart) {
    int b = blockIdx.x;
    int t = threadIdx.x;
    int i = b * 256 + t;
    __shared__ int s[256];
    int v = (i < NNODES) ? deg[i] : 0;
    s[t] = v;
    __syncthreads();
    for (int off = 1; off < 256; off <<= 1) {
        int u = (t >= off) ? s[t - off] : 0;
        __syncthreads();
        s[t] += u;
        __syncthreads();
    }
    if (i < NNODES) {
        int ex = partials[b] + s[t] - v;
        rowptr[i] = ex;
        cursor[i] = ex;
        int bb = batch[i];
        int bp = (i == 0) ? -1 : batch[i - 1];
        for (int g = bp + 1; g <= bb; ++g) gstart[g] = i;
        if (i == NNODES - 1)
            for (int g = bb + 1; g <= NGRAPHS; ++g) gstart[g] = NNODES;
    }
    if (b == 0 && t == 0) rowptr[NNODES] = NEDGES;  // sum(deg) == NEDGES
}

__global__ __launch_bounds__(256) void fill_kernel(const int* __restrict__ srcA,
                                                   const int* __restrict__ dstA,
                                                   int* __restrict__ cursor,
                                                   int* __restrict__ adj) {
    int e = blockIdx.x * 256 + threadIdx.x;
    if (e < NEDGES) {
        int d = dstA[e];
        int loc = atomicAdd(&cursor[d], 1);
        adj[loc] = srcA[e];
    }
}

// ------- gather aggregation: agg[n] = x[n] + sum_{s in adj[n]} x[s] (+bias) -------
template <int DIM, int CHUNK, int OSTRIDE>
__global__ __launch_bounds__(256) void gather_kernel(const float* __restrict__ x,
                                                     const int* __restrict__ rowptr,
                                                     const int* __restrict__ adj,
                                                     float* __restrict__ agg,
                                                     const float* __restrict__ bias) {
    constexpr int PE = DIM / CHUNK;
    int gid = blockIdx.x * 256 + threadIdx.x;
    if (gid >= NNODES * PE) return;
    int node = gid / PE;
    int c = gid - node * PE;
    const int beg = rowptr[node];
    const int end = rowptr[node + 1];
    if (CHUNK == 4) {
        const float4* xp = (const float4*)x;
        float4 acc = xp[(size_t)node * PE + c];
        for (int i = beg; i < end; ++i) {
            int s = adj[i];
            float4 v = xp[(size_t)s * PE + c];
            acc.x += v.x;
            acc.y += v.y;
            acc.z += v.z;
            acc.w += v.w;
        }
        if (bias) {
            float4 b = *(const float4*)&bias[c * 4];
            acc.x += b.x; acc.y += b.y; acc.z += b.z; acc.w += b.w;
        }
        *(float4*)&agg[(size_t)node * OSTRIDE + c * 4] = acc;
    } else {
        const float2* xp = (const float2*)x;
        float2 acc = xp[(size_t)node * PE + c];
        for (int i = beg; i < end; ++i) {
            int s = adj[i];
            float2 v = xp[(size_t)s * PE + c];
            acc.x += v.x;
            acc.y += v.y;
        }
        *(float2*)&agg[(size_t)node * OSTRIDE + c * 2] = acc;
    }
}

// ---------------- BN stats (standalone, used once for L2) ----------------
template <int N>
__global__ __launch_bounds__(256) void bnstats_kernel(const float* __restrict__ h,
                                                      float* __restrict__ sums) {
    constexpr int SHIFT = (N == 128) ? 7 : 8;
    int t = blockIdx.x * 256 + threadIdx.x;
    int col = t & (N - 1);
    int slice = t >> SHIFT;
    float s = 0.f, s2 = 0.f;
    for (int r = slice; r < NNODES; r += 256) {
        float v = h[(size_t)r * N + col];
        s += v;
        s2 += v * v;
    }
    atomicAdd(&sums[col], s);
    atomicAdd(&sums[256 + col], s2);
}

// reads sums (sum@c, sumsq@256+c), writes scale@c / shift@256+c, then re-zeroes sums.
__global__ void bnfinal_kernel(float* __restrict__ sums, const float* __restrict__ gamma,
                               const float* __restrict__ beta, float* __restrict__ scsh, int N,
                               float invM) {
    int c = threadIdx.x;  // 256 threads always
    if (c < N) {
        float mean = sums[c] * invM;
        float var = sums[256 + c] * invM - mean * mean;
        float sc = gamma[c] * rsqrtf(var + BN_EPS);
        scsh[c] = sc;
        scsh[256 + c] = beta[c] - mean * sc;
    }
    sums[c] = 0.f;
    sums[256 + c] = 0.f;
}

__device__ __forceinline__ void fma44(float (&cc)[4][4], const float4& a, const float4& b) {
    cc[0][0] += a.x * b.x; cc[0][1] += a.x * b.y; cc[0][2] += a.x * b.z; cc[0][3] += a.x * b.w;
    cc[1][0] += a.y * b.x; cc[1][1] += a.y * b.y; cc[1][2] += a.y * b.z; cc[1][3] += a.y * b.w;
    cc[2][0] += a.z * b.x; cc[2][1] += a.z * b.y; cc[2][2] += a.z * b.z; cc[2][3] += a.z * b.w;
    cc[3][0] += a.w * b.x; cc[3][1] += a.w * b.y; cc[3][2] += a.w * b.z; cc[3][3] += a.w * b.w;
}

// ---------------- 128x64 tile fp32 GEMM, 8x4/thread (R7-proven) ----------
template <bool BNRELU_A, bool RELU_OUT, bool FUSE_STATS>
__global__ __launch_bounds__(256) void gemm128x64_kernel(
    const float* __restrict__ A, const float* __restrict__ W, const float* __restrict__ bias,
    const float* __restrict__ scsh, float* __restrict__ C, float* __restrict__ stats, int M,
    int K, int Kw, int N) {
    __shared__ __align__(16) float As[16][132];
    __shared__ __align__(16) float Bs[16][64];
    __shared__ float sstat[128];
    const int tid = threadIdx.x;
    const int tx = tid & 15;
    const int ty = tid >> 4;
    const int m0 = blockIdx.x * 128;
    const int n0 = blockIdx.y * 64;

    if (FUSE_STATS && tid < 128) sstat[tid] = 0.f;

    float c[2][4][4] = {};

    for (int k0 = 0; k0 < K; k0 += 16) {
#pragma unroll
        for (int i = 0; i < 2; ++i) {
            int lin4 = tid + i * 256;
            int row = lin4 >> 2;
            int kq = lin4 & 3;
            int gm = m0 + row;
            float4 v = make_float4(0.f, 0.f, 0.f, 0.f);
            if (gm < M) v = *(const float4*)&A[(size_t)gm * K + k0 + kq * 4];
            if (BNRELU_A) {
                int gk = k0 + kq * 4;
                v.x = fmaxf(v.x * scsh[gk + 0] + scsh[256 + gk + 0], 0.f);
                v.y = fmaxf(v.y * scsh[gk + 1] + scsh[256 + gk + 1], 0.f);
                v.z = fmaxf(v.z * scsh[gk + 2] + scsh[256 + gk + 2], 0.f);
                v.w = fmaxf(v.w * scsh[gk + 3] + scsh[256 + gk + 3], 0.f);
            }
            As[kq * 4 + 0][row] = v.x;
            As[kq * 4 + 1][row] = v.y;
            As[kq * 4 + 2][row] = v.z;
            As[kq * 4 + 3][row] = v.w;
        }
        {
            int kr = tid >> 4;
            int nq = tid & 15;
            int gk = k0 + kr;
            float4 v = make_float4(0.f, 0.f, 0.f, 0.f);
            if (gk < Kw) v = *(const float4*)&W[(size_t)gk * N + n0 + nq * 4];
            *(float4*)&Bs[kr][nq * 4] = v;
        }
        __syncthreads();
        float4 a0 = *(const float4*)&As[0][ty * 4];
        float4 a1 = *(const float4*)&As[0][64 + ty * 4];
        float4 b = *(const float4*)&Bs[0][tx * 4];
#pragma unroll
        for (int kk = 0; kk < 16; ++kk) {
            float4 na0, na1, nb;
            if (kk < 15) {
                na0 = *(const float4*)&As[kk + 1][ty * 4];
                na1 = *(const float4*)&As[kk + 1][64 + ty * 4];
                nb = *(const float4*)&Bs[kk + 1][tx * 4];
            }
            fma44(c[0], a0, b);
            fma44(c[1], a1, b);
            if (kk < 15) {
                a0 = na0;
                a1 = na1;
                b = nb;
            }
        }
        __syncthreads();
    }

    float s_sum[4] = {}, s_sq[4] = {};
    const bool hasb = (bias != nullptr);
    const int gn = n0 + tx * 4;
    float4 bv = make_float4(0.f, 0.f, 0.f, 0.f);
    if (hasb) bv = *(const float4*)&bias[gn];
#pragma unroll
    for (int qa = 0; qa < 2; ++qa) {
#pragma unroll
        for (int i = 0; i < 4; ++i) {
            int gm = m0 + qa * 64 + ty * 4 + i;
            if (gm >= M) continue;
            float4 v;
            v.x = c[qa][i][0] + bv.x;
            v.y = c[qa][i][1] + bv.y;
            v.z = c[qa][i][2] + bv.z;
            v.w = c[qa][i][3] + bv.w;
            if (RELU_OUT) {
                v.x = fmaxf(v.x, 0.f); v.y = fmaxf(v.y, 0.f);
                v.z = fmaxf(v.z, 0.f); v.w = fmaxf(v.w, 0.f);
            }
            *(float4*)&C[(size_t)gm * N + gn] = v;
            if (FUSE_STATS) {
                s_sum[0] += v.x; s_sq[0] += v.x * v.x;
                s_sum[1] += v.y; s_sq[1] += v.y * v.y;
                s_sum[2] += v.z; s_sq[2] += v.z * v.z;
                s_sum[3] += v.w; s_sq[3] += v.w * v.w;
            }
        }
    }
    if (FUSE_STATS) {
#pragma unroll
        for (int j = 0; j < 4; ++j) {
            int cl = tx * 4 + j;
            atomicAdd(&sstat[cl], s_sum[j]);
            atomicAdd(&sstat[64 + cl], s_sq[j]);
        }
        __syncthreads();
        if (tid < 64) {
            atomicAdd(&stats[n0 + tid], sstat[tid]);
            atomicAdd(&stats[256 + n0 + tid], sstat[64 + tid]);
        }
    }
}

// ---------------- 64x64 tile fp32 GEMM w/ prefetch (fc0 + fc1 split-K stage) -------------
// KOFF: if true, blockIdx.z selects a 64-wide K-chunk and C is a partial buffer
// (chunk-strided), no bias. R10 evidence: fc1 at grid=(32,2) was 64 blocks / 2.9% occ /
// 175us pure latency; split-K gives 1024 blocks and 4 k-iters each.
template <bool RELU_OUT, bool KOFF>
__global__ __launch_bounds__(256) void gemm64_kernel(const float* __restrict__ A,
                                                     const float* __restrict__ W,
                                                     const float* __restrict__ bias,
                                                     float* __restrict__ C, int M, int K, int N) {
    __shared__ __align__(16) float As[16][68];
    __shared__ __align__(16) float Bs[16][64];
    const int tid = threadIdx.x;
    const int tx = tid & 15;
    const int ty = tid >> 4;
    const int m0 = blockIdx.x * 64;
    const int n0 = blockIdx.y * 64;
    const int kbeg = KOFF ? blockIdx.z * 64 : 0;
    const int kend = KOFF ? kbeg + 64 : K;

    float c[4][4] = {};

    for (int k0 = kbeg; k0 < kend; k0 += 16) {
#pragma unroll
        for (int i = 0; i < 4; ++i) {
            int lin = tid + i * 256;
            int m = lin >> 4;
            int k = lin & 15;
            int gm = m0 + m;
            int gk = k0 + k;
            float v = 0.f;
            if (gm < M && gk < K) v = A[(size_t)gm * K + gk];
            As[k][m] = v;
        }
#pragma unroll
        for (int i = 0; i < 4; ++i) {
            int lin = tid + i * 256;
            int k = lin >> 6;
            int n = lin & 63;
            int gk = k0 + k;
            float v = 0.f;
            if (gk < K) v = W[(size_t)gk * N + n0 + n];
            Bs[k][n] = v;
        }
        __syncthreads();
        float4 a = *(const float4*)&As[0][ty * 4];
        float4 b = *(const float4*)&Bs[0][tx * 4];
#pragma unroll
        for (int kk = 0; kk < 16; ++kk) {
            float4 na, nb;
            if (kk < 15) {
                na = *(const float4*)&As[kk + 1][ty * 4];
                nb = *(const float4*)&Bs[kk + 1][tx * 4];
            }
            fma44(c, a, b);
            if (kk < 15) {
                a = na;
                b = nb;
            }
        }
        __syncthreads();
    }

    float* Cb = KOFF ? C + (size_t)blockIdx.z * M * N : C;
#pragma unroll
    for (int i = 0; i < 4; ++i) {
        int gm = m0 + ty * 4 + i;
        if (gm >= M) continue;
#pragma unroll
        for (int j = 0; j < 4; ++j) {
            int gn = n0 + tx * 4 + j;
            float v = c[i][j] + (KOFF ? 0.f : bias[gn]);
            if (RELU_OUT) v = fmaxf(v, 0.f);
            Cb[(size_t)gm * N + gn] = v;
        }
    }
}

// ---- reduce 16 split-K partials + bias -> out (fc1: M=2048,N=128) ----
__global__ __launch_bounds__(256) void splitk_reduce_kernel(const float* __restrict__ part,
                                                            const float* __restrict__ bias,
                                                            float* __restrict__ out) {
    const int i4 = blockIdx.x * 256 + threadIdx.x;  // float4 index over M*N/4
    const int TOT4 = NGRAPHS * 128 / 4;             // 65536
    if (i4 >= TOT4) return;
    const float4* p = (const float4*)part;
    float4 acc = make_float4(0.f, 0.f, 0.f, 0.f);
#pragma unroll
    for (int c = 0; c < 16; ++c) {
        float4 v = p[(size_t)c * TOT4 + i4];
        acc.x += v.x; acc.y += v.y; acc.z += v.z; acc.w += v.w;
    }
    float4 b = ((const float4*)bias)[i4 & 31];  // 128 cols = 32 float4 per row
    acc.x += b.x; acc.y += b.y; acc.z += b.z; acc.w += b.w;
    ((float4*)out)[i4] = acc;
}

// ---- segmented pool over sorted batch ----
__global__ __launch_bounds__(128) void pool_seg_kernel(const float* __restrict__ h,
                                                       const int* __restrict__ gstart,
                                                       float* __restrict__ g) {
    int gr = blockIdx.x;
    int t = threadIdx.x;  // column 0..127
    int beg = gstart[gr];
    int end = gstart[gr + 1];
    float acc = 0.f;
    for (int r = beg; r < end; ++r) acc += h[(size_t)r * 128 + t];
    g[(size_t)gr * 128 + t] = acc;
}

extern "C" void kernel_launch(void* const* d_in, const int* in_sizes, int n_in, void* d_out,
                              int out_size, void* d_ws, size_t ws_size, hipStream_t stream) {
    const float* x = (const float*)d_in[0];
    const int* ei = (const int*)d_in[1];
    const int* batch = (const int*)d_in[2];
    const int* srcA = ei;
    const int* dstA = ei + NEDGES;

    const float* g0_w1 = (const float*)d_in[3];
    const float* g0_b1 = (const float*)d_in[4];
    const float* g0_ga = (const float*)d_in[5];
    const float* g0_be = (const float*)d_in[6];
    const float* g0_w2 = (const float*)d_in[7];
    const float* g0_b2 = (const float*)d_in[8];
    const float* g1_w1 = (const float*)d_in[9];
    const float* g1_b1 = (const float*)d_in[10];
    const float* g1_ga = (const float*)d_in[11];
    const float* g1_be = (const float*)d_in[12];
    const float* g1_w2 = (const float*)d_in[13];
    const float* g1_b2 = (const float*)d_in[14];
    const float* g2_w1 = (const float*)d_in[15];
    const float* g2_b1 = (const float*)d_in[16];
    const float* g2_ga = (const float*)d_in[17];
    const float* g2_be = (const float*)d_in[18];
    const float* g2_w2 = (const float*)d_in[19];
    const float* g2_b2 = (const float*)d_in[20];
    const float* fc0_w = (const float*)d_in[21];
    const float* fc0_b = (const float*)d_in[22];
    const float* fc1_w = (const float*)d_in[23];
    const float* fc1_b = (const float*)d_in[24];

    // --- workspace layout (~222 MB) ---
    float* ws = (float*)d_ws;
    const size_t BUF = (size_t)NNODES * 256;
    float* R0 = ws;
    float* R1 = R0 + BUF;  // ALSO reused as fc1 split-K partial buffer (16*2048*128 = 4.2M < BUF)
    float* stats = R1 + BUF;                         // 512
    float* scsh = stats + 512;                       // 512
    float* g = scsh + 512;                           // 2048*128 pooled
    float* gh = g + (size_t)NGRAPHS * 128;           // 2048*1024 fc hidden
    int* deg = (int*)(gh + (size_t)NGRAPHS * 1024);  // NNODES
    int* rowptr = deg + NNODES;                      // NNODES+1
    int* cursor = rowptr + NNODES + 4;               // NNODES
    int* adj = cursor + NNODES;                      // NEDGES
    int* partials = adj + NEDGES;                    // 391
    int* gstart = partials + 512;                    // NGRAPHS+1

    const int MB = (NNODES + 127) / 128;  // 782 row-blocks
    const int NB = (NNODES + 255) / 256;  // 391 scan blocks

    // --- build CSR + graph bounds once ---
    hipMemsetAsync(deg, 0, NNODES * sizeof(int), stream);
    hipMemsetAsync(stats, 0, 512 * sizeof(float), stream);  // bnfinal re-zeroes thereafter
    deg_kernel<<<(NEDGES + 255) / 256, 256, 0, stream>>>(dstA, deg);
    scan1_kernel<<<NB, 256, 0, stream>>>(deg, partials);
    scan2_kernel<<<1, 512, 0, stream>>>(partials, NB);
    scan3_kernel<<<NB, 256, 0, stream>>>(deg, partials, rowptr, cursor, batch, gstart);
    fill_kernel<<<(NEDGES + 255) / 256, 256, 0, stream>>>(srcA, dstA, cursor, adj);

    // ================= Layer 0 (66 -> 128 -> 128) =================
    gather_kernel<66, 2, 68><<<(NNODES * 33 + 255) / 256, 256, 0, stream>>>(x, rowptr, adj, R0,
                                                                            nullptr);
    gemm128x64_kernel<false, false, true><<<dim3(MB, 2), 256, 0, stream>>>(
        R0, g0_w1, g0_b1, nullptr, R1, stats, NNODES, 68, 66, 128);
    bnfinal_kernel<<<1, 256, 0, stream>>>(stats, g0_ga, g0_be, scsh, 128, 1.0f / NNODES);
    gemm128x64_kernel<true, true, false><<<dim3(MB, 2), 256, 0, stream>>>(
        R1, g0_w2, g0_b2, scsh, R0, nullptr, NNODES, 128, 128, 128);

    // ================= Layer 1 (128 -> 256 -> 256) =================
    gather_kernel<128, 4, 128><<<(NNODES * 32 + 255) / 256, 256, 0, stream>>>(R0, rowptr, adj, R1,
                                                                              nullptr);
    gemm128x64_kernel<false, false, true><<<dim3(MB, 2), 256, 0, stream>>>(
        R1, g1_w1, g1_b1, nullptr, R0, stats, NNODES, 128, 128, 256);
    gemm128x64_kernel<false, false, true><<<dim3(MB, 2), 256, 0, stream>>>(
        R1, g1_w1 + 128, g1_b1 + 128, nullptr, R0 + 128, stats + 128, NNODES, 128, 128, 256);
    bnfinal_kernel<<<1, 256, 0, stream>>>(stats, g1_ga, g1_be, scsh, 256, 1.0f / NNODES);
    gemm128x64_kernel<true, true, false><<<dim3(MB, 2), 256, 0, stream>>>(
        R0, g1_w2, g1_b2, scsh, R1, nullptr, NNODES, 256, 256, 256);
    gemm128x64_kernel<true, true, false><<<dim3(MB, 2), 256, 0, stream>>>(
        R0, g1_w2 + 128, g1_b2 + 128, scsh, R1 + 128, nullptr, NNODES, 256, 256, 256);

    // ================= Layer 2 (256 -> 128 -> 128), REORDERED =================
    gemm128x64_kernel<false, false, false><<<dim3(MB, 2), 256, 0, stream>>>(
        R1, g2_w1, nullptr, nullptr, R0, nullptr, NNODES, 256, 256, 128);
    gather_kernel<128, 4, 128><<<(NNODES * 32 + 255) / 256, 256, 0, stream>>>(R0, rowptr, adj, R1,
                                                                              g2_b1);
    bnstats_kernel<128><<<128, 256, 0, stream>>>(R1, stats);
    bnfinal_kernel<<<1, 256, 0, stream>>>(stats, g2_ga, g2_be, scsh, 128, 1.0f / NNODES);
    gemm128x64_kernel<true, true, false><<<dim3(MB, 2), 256, 0, stream>>>(
        R1, g2_w2, g2_b2, scsh, R0, nullptr, NNODES, 128, 128, 128);

    // ================= pool (segmented, no atomics) + FC head =================
    pool_seg_kernel<<<NGRAPHS, 128, 0, stream>>>(R0, gstart, g);

    // fc0: relu(g @ fc0_w + fc0_b) -> gh  (2048x128 @ 128x1024); 512 blocks, prefetched
    gemm64_kernel<true, false><<<dim3(NGRAPHS / 64, 1024 / 64), 256, 0, stream>>>(
        g, fc0_w, fc0_b, gh, NGRAPHS, 128, 1024);
    // fc1 split-K: 16 chunks of 64 -> partials in R1 (R1 is dead here), then reduce+bias.
    gemm64_kernel<false, true><<<dim3(NGRAPHS / 64, 128 / 64, 16), 256, 0, stream>>>(
        gh, fc1_w, nullptr, R1, NGRAPHS, 1024, 128);
    splitk_reduce_kernel<<<(NGRAPHS * 128 / 4 + 255) / 256, 256, 0, stream>>>(R1, fc1_b,
                                                                              (float*)d_out);
}

// Round 12
// 1365.849 us; speedup vs baseline: 1.4990x; 1.1315x over previous
//
#include <hip/hip_runtime.h>

#define NNODES 100000
#define NEDGES 1600000
#define NGRAPHS 2048
#define BN_EPS 1e-5f

typedef __attribute__((ext_vector_type(8))) short bf16x8;
typedef __attribute__((ext_vector_type(4))) float f32x4;

// RNE float -> bf16 (as short bits)
__device__ __forceinline__ short f2bf(float x) {
    unsigned u = __float_as_uint(x);
    unsigned r = u + 0x7FFF + ((u >> 16) & 1);
    return (short)(r >> 16);
}
__device__ __forceinline__ float bf2f(short h) {
    return __uint_as_float(((unsigned)(unsigned short)h) << 16);
}

// ---------------- CSR build ----------------
__global__ __launch_bounds__(256) void deg_kernel(const int* __restrict__ dstA,
                                                  int* __restrict__ deg) {
    int e = blockIdx.x * 256 + threadIdx.x;
    if (e < NEDGES) atomicAdd(&deg[dstA[e]], 1);
}

__global__ __launch_bounds__(256) void scan1_kernel(const int* __restrict__ deg,
                                                    int* __restrict__ partials) {
    int b = blockIdx.x;
    int i = b * 256 + threadIdx.x;
    int v = (i < NNODES) ? deg[i] : 0;
    __shared__ int wsum[4];
#pragma unroll
    for (int off = 32; off; off >>= 1) v += __shfl_down(v, off);
    if ((threadIdx.x & 63) == 0) wsum[threadIdx.x >> 6] = v;
    __syncthreads();
    if (threadIdx.x == 0) partials[b] = wsum[0] + wsum[1] + wsum[2] + wsum[3];
}

__global__ __launch_bounds__(512) void scan2_kernel(int* __restrict__ partials, int nb) {
    __shared__ int s[512];
    int t = threadIdx.x;
    int v = (t < nb) ? partials[t] : 0;
    s[t] = v;
    __syncthreads();
    for (int off = 1; off < 512; off <<= 1) {
        int u = (t >= off) ? s[t - off] : 0;
        __syncthreads();
        s[t] += u;
        __syncthreads();
    }
    if (t < nb) partials[t] = s[t] - v;  // exclusive
}

__global__ __launch_bounds__(256) void scan3_kernel(const int* __restrict__ deg,
                                                    const int* __restrict__ partials,
                                                    int* __restrict__ rowptr,
                                                    int* __restrict__ cursor,
                                                    const int* __restrict__ batch,
                                                    int* __restrict__ gstart) {
    int b = blockIdx.x;
    int t = threadIdx.x;
    int i = b * 256 + t;
    __shared__ int s[256];
    int v = (i < NNODES) ? deg[i] : 0;
    s[t] = v;
    __syncthreads();
    for (int off = 1; off < 256; off <<= 1) {
        int u = (t >= off) ? s[t - off] : 0;
        __syncthreads();
        s[t] += u;
        __syncthreads();
    }
    if (i < NNODES) {
        int ex = partials[b] + s[t] - v;
        rowptr[i] = ex;
        cursor[i] = ex;
        int bb = batch[i];
        int bp = (i == 0) ? -1 : batch[i - 1];
        for (int g = bp + 1; g <= bb; ++g) gstart[g] = i;
        if (i == NNODES - 1)
            for (int g = bb + 1; g <= NGRAPHS; ++g) gstart[g] = NNODES;
    }
    if (b == 0 && t == 0) rowptr[NNODES] = NEDGES;
}

__global__ __launch_bounds__(256) void fill_kernel(const int* __restrict__ srcA,
                                                   const int* __restrict__ dstA,
                                                   int* __restrict__ cursor,
                                                   int* __restrict__ adj) {
    int e = blockIdx.x * 256 + threadIdx.x;
    if (e < NEDGES) {
        int d = dstA[e];
        int loc = atomicAdd(&cursor[d], 1);
        adj[loc] = srcA[e];
    }
}

// ------- gather aggregation: agg[n] = x[n] + sum_{s in adj[n]} x[s] (+bias) -------
template <int DIM, int CHUNK, int OSTRIDE>
__global__ __launch_bounds__(256) void gather_kernel(const float* __restrict__ x,
                                                     const int* __restrict__ rowptr,
                                                     const int* __restrict__ adj,
                                                     float* __restrict__ agg,
                                                     const float* __restrict__ bias) {
    constexpr int PE = DIM / CHUNK;
    int gid = blockIdx.x * 256 + threadIdx.x;
    if (gid >= NNODES * PE) return;
    int node = gid / PE;
    int c = gid - node * PE;
    const int beg = rowptr[node];
    const int end = rowptr[node + 1];
    if (CHUNK == 4) {
        const float4* xp = (const float4*)x;
        float4 acc = xp[(size_t)node * PE + c];
        for (int i = beg; i < end; ++i) {
            int s = adj[i];
            float4 v = xp[(size_t)s * PE + c];
            acc.x += v.x;
            acc.y += v.y;
            acc.z += v.z;
            acc.w += v.w;
        }
        if (bias) {
            float4 b = *(const float4*)&bias[c * 4];
            acc.x += b.x; acc.y += b.y; acc.z += b.z; acc.w += b.w;
        }
        *(float4*)&agg[(size_t)node * OSTRIDE + c * 4] = acc;
    } else {
        const float2* xp = (const float2*)x;
        float2 acc = xp[(size_t)node * PE + c];
        for (int i = beg; i < end; ++i) {
            int s = adj[i];
            float2 v = xp[(size_t)s * PE + c];
            acc.x += v.x;
            acc.y += v.y;
        }
        *(float2*)&agg[(size_t)node * OSTRIDE + c * 2] = acc;
    }
}

// ---------------- BN stats (standalone, used once for L2) ----------------
template <int N>
__global__ __launch_bounds__(256) void bnstats_kernel(const float* __restrict__ h,
                                                      float* __restrict__ sums) {
    constexpr int SHIFT = (N == 128) ? 7 : 8;
    int t = blockIdx.x * 256 + threadIdx.x;
    int col = t & (N - 1);
    int slice = t >> SHIFT;
    float s = 0.f, s2 = 0.f;
    for (int r = slice; r < NNODES; r += 256) {
        float v = h[(size_t)r * N + col];
        s += v;
        s2 += v * v;
    }
    atomicAdd(&sums[col], s);
    atomicAdd(&sums[256 + col], s2);
}

// reads sums (sum@c, sumsq@256+c), writes scale@c / shift@256+c, then re-zeroes sums.
__global__ void bnfinal_kernel(float* __restrict__ sums, const float* __restrict__ gamma,
                               const float* __restrict__ beta, float* __restrict__ scsh, int N,
                               float invM) {
    int c = threadIdx.x;  // 256 threads always
    if (c < N) {
        float mean = sums[c] * invM;
        float var = sums[256 + c] * invM - mean * mean;
        float sc = gamma[c] * rsqrtf(var + BN_EPS);
        scsh[c] = sc;
        scsh[256 + c] = beta[c] - mean * sc;
    }
    sums[c] = 0.f;
    sums[256 + c] = 0.f;
}

// ---- W pre-pass: decompose W (Kw x N fp32) into hi/lo bf16 B-fragments ----
// Fragment layout (mfma_f32_16x16x32_bf16 B-operand): lane holds n=lane&15,
// k = (lane>>4)*8 + j. Buffer index: ((nt*KT + kt)*64 + lane)*8 + j.
__global__ __launch_bounds__(256) void wprep_kernel(const float* __restrict__ W, int Kw, int N,
                                                    int KT, short* __restrict__ whi,
                                                    short* __restrict__ wlo) {
    int idx = blockIdx.x * 256 + threadIdx.x;
    int total = (N >> 4) * KT * 512;
    if (idx >= total) return;
    int j = idx & 7;
    int lane = (idx >> 3) & 63;
    int t = idx >> 9;  // nt*KT + kt
    int kt = t % KT;
    int nt = t / KT;
    int k = kt * 32 + ((lane >> 4) << 3) + j;
    int n = (nt << 4) + (lane & 15);
    float w = (k < Kw) ? W[(size_t)k * N + n] : 0.f;
    short hi = f2bf(w);
    short lo = f2bf(w - bf2f(hi));
    whi[idx] = hi;
    wlo[idx] = lo;
}

// ---------------- split-bf16 MFMA GEMM: C = op(A) @ W + bias ----------------
// LDS-free. Block = 256 thr = 4 waves; BM=64 (16 rows/wave); NT = N/16 tiles per wave.
// A: M x Kst fp32 row-major; lane loads its A-frag (m=lane&15, k=quad*8+j) as 2 float4,
// decomposes to hi/lo bf16 in regs. B-frags preformatted by wprep (global, L1/L2-hot).
// 4 mfma cross-terms per (kt, nt): exact to ~2^-19 representation error.
// Rows >= M read finite garbage (in-workspace); stores/stats guarded by gm < M.
template <int NT, bool BNRELU_A, bool RELU_OUT, bool FUSE_STATS>
__global__ __launch_bounds__(256) void gemm_mfma_kernel(
    const float* __restrict__ A, const short* __restrict__ whi, const short* __restrict__ wlo,
    const float* __restrict__ bias, const float* __restrict__ scsh, float* __restrict__ C,
    float* __restrict__ stats, int M, int Kst, int KT, int N) {
    __shared__ float sstat[512];
    const int tid = threadIdx.x;
    const int wave = tid >> 6;
    const int lane = tid & 63;
    const int quad = lane >> 4;
    const int l16 = lane & 15;
    const int mrow = blockIdx.x * 64 + wave * 16 + l16;  // A-frag row for this lane

    if (FUSE_STATS) {
        sstat[tid] = 0.f;
        sstat[tid + 256] = 0.f;
        __syncthreads();
    }

    f32x4 acc[NT] = {};

    for (int kt = 0; kt < KT; ++kt) {
        const int kq = kt * 32 + quad * 8;
        const float* ap = A + (size_t)mrow * Kst + kq;
        float4 x0 = *(const float4*)ap;
        float4 x1 = *(const float4*)(ap + 4);
        float a8[8] = {x0.x, x0.y, x0.z, x0.w, x1.x, x1.y, x1.z, x1.w};
        if (BNRELU_A) {
            float4 sc0 = *(const float4*)&scsh[kq];
            float4 sc1 = *(const float4*)&scsh[kq + 4];
            float4 sh0 = *(const float4*)&scsh[256 + kq];
            float4 sh1 = *(const float4*)&scsh[256 + kq + 4];
            float sc[8] = {sc0.x, sc0.y, sc0.z, sc0.w, sc1.x, sc1.y, sc1.z, sc1.w};
            float sh[8] = {sh0.x, sh0.y, sh0.z, sh0.w, sh1.x, sh1.y, sh1.z, sh1.w};
#pragma unroll
            for (int i = 0; i < 8; ++i) a8[i] = fmaxf(a8[i] * sc[i] + sh[i], 0.f);
        }
        bf16x8 ahi, alo;
#pragma unroll
        for (int i = 0; i < 8; ++i) {
            short h = f2bf(a8[i]);
            ahi[i] = h;
            alo[i] = f2bf(a8[i] - bf2f(h));
        }
#pragma unroll
        for (int nt = 0; nt < NT; ++nt) {
            const size_t boff = (((size_t)nt * KT + kt) << 9) + (lane << 3);
            bf16x8 bh = *(const bf16x8*)(whi + boff);
            bf16x8 bl = *(const bf16x8*)(wlo + boff);
            acc[nt] = __builtin_amdgcn_mfma_f32_16x16x32_bf16(ahi, bh, acc[nt], 0, 0, 0);
            acc[nt] = __builtin_amdgcn_mfma_f32_16x16x32_bf16(alo, bh, acc[nt], 0, 0, 0);
            acc[nt] = __builtin_amdgcn_mfma_f32_16x16x32_bf16(ahi, bl, acc[nt], 0, 0, 0);
            acc[nt] = __builtin_amdgcn_mfma_f32_16x16x32_bf16(alo, bl, acc[nt], 0, 0, 0);
        }
    }

    // Epilogue. C/D frag: col = l16 (+16*nt), row = quad*4 + reg (m89-verified).
    const int mbase = blockIdx.x * 64 + wave * 16 + quad * 4;
#pragma unroll
    for (int nt = 0; nt < NT; ++nt) {
        int gn = nt * 16 + l16;
        float bv = bias ? bias[gn] : 0.f;
        float s = 0.f, s2 = 0.f;
#pragma unroll
        for (int r = 0; r < 4; ++r) {
            int gm = mbase + r;
            float v = acc[nt][r] + bv;
            if (RELU_OUT) v = fmaxf(v, 0.f);
            if (gm < M) {
                C[(size_t)gm * N + gn] = v;
                if (FUSE_STATS) {
                    s += v;
                    s2 += v * v;
                }
            }
        }
        if (FUSE_STATS) {
            s += __shfl_xor(s, 16);
            s += __shfl_xor(s, 32);
            s2 += __shfl_xor(s2, 16);
            s2 += __shfl_xor(s2, 32);
            if (quad == 0) {
                atomicAdd(&sstat[gn], s);
                atomicAdd(&sstat[256 + gn], s2);
            }
        }
    }
    if (FUSE_STATS) {
        __syncthreads();
        if (tid < N) {
            atomicAdd(&stats[tid], sstat[tid]);
            atomicAdd(&stats[256 + tid], sstat[256 + tid]);
        }
    }
}

__device__ __forceinline__ void fma44(float (&cc)[4][4], const float4& a, const float4& b) {
    cc[0][0] += a.x * b.x; cc[0][1] += a.x * b.y; cc[0][2] += a.x * b.z; cc[0][3] += a.x * b.w;
    cc[1][0] += a.y * b.x; cc[1][1] += a.y * b.y; cc[1][2] += a.y * b.z; cc[1][3] += a.y * b.w;
    cc[2][0] += a.z * b.x; cc[2][1] += a.z * b.y; cc[2][2] += a.z * b.z; cc[2][3] += a.z * b.w;
    cc[3][0] += a.w * b.x; cc[3][1] += a.w * b.y; cc[3][2] += a.w * b.z; cc[3][3] += a.w * b.w;
}

// ---------------- 64x64 tile fp32 GEMM w/ prefetch (fc0 + fc1 split-K stage) -------------
template <bool RELU_OUT, bool KOFF>
__global__ __launch_bounds__(256) void gemm64_kernel(const float* __restrict__ A,
                                                     const float* __restrict__ W,
                                                     const float* __restrict__ bias,
                                                     float* __restrict__ C, int M, int K, int N) {
    __shared__ __align__(16) float As[16][68];
    __shared__ __align__(16) float Bs[16][64];
    const int tid = threadIdx.x;
    const int tx = tid & 15;
    const int ty = tid >> 4;
    const int m0 = blockIdx.x * 64;
    const int n0 = blockIdx.y * 64;
    const int kbeg = KOFF ? blockIdx.z * 64 : 0;
    const int kend = KOFF ? kbeg + 64 : K;

    float c[4][4] = {};

    for (int k0 = kbeg; k0 < kend; k0 += 16) {
#pragma unroll
        for (int i = 0; i < 4; ++i) {
            int lin = tid + i * 256;
            int m = lin >> 4;
            int k = lin & 15;
            int gm = m0 + m;
            int gk = k0 + k;
            float v = 0.f;
            if (gm < M && gk < K) v = A[(size_t)gm * K + gk];
            As[k][m] = v;
        }
#pragma unroll
        for (int i = 0; i < 4; ++i) {
            int lin = tid + i * 256;
            int k = lin >> 6;
            int n = lin & 63;
            int gk = k0 + k;
            float v = 0.f;
            if (gk < K) v = W[(size_t)gk * N + n0 + n];
            Bs[k][n] = v;
        }
        __syncthreads();
        float4 a = *(const float4*)&As[0][ty * 4];
        float4 b = *(const float4*)&Bs[0][tx * 4];
#pragma unroll
        for (int kk = 0; kk < 16; ++kk) {
            float4 na, nb;
            if (kk < 15) {
                na = *(const float4*)&As[kk + 1][ty * 4];
                nb = *(const float4*)&Bs[kk + 1][tx * 4];
            }
            fma44(c, a, b);
            if (kk < 15) {
                a = na;
                b = nb;
            }
        }
        __syncthreads();
    }

    float* Cb = KOFF ? C + (size_t)blockIdx.z * M * N : C;
#pragma unroll
    for (int i = 0; i < 4; ++i) {
        int gm = m0 + ty * 4 + i;
        if (gm >= M) continue;
#pragma unroll
        for (int j = 0; j < 4; ++j) {
            int gn = n0 + tx * 4 + j;
            float v = c[i][j] + (KOFF ? 0.f : bias[gn]);
            if (RELU_OUT) v = fmaxf(v, 0.f);
            Cb[(size_t)gm * N + gn] = v;
        }
    }
}

// ---- reduce 16 split-K partials + bias -> out (fc1: M=2048,N=128) ----
__global__ __launch_bounds__(256) void splitk_reduce_kernel(const float* __restrict__ part,
                                                            const float* __restrict__ bias,
                                                            float* __restrict__ out) {
    const int i4 = blockIdx.x * 256 + threadIdx.x;
    const int TOT4 = NGRAPHS * 128 / 4;  // 65536
    if (i4 >= TOT4) return;
    const float4* p = (const float4*)part;
    float4 acc = make_float4(0.f, 0.f, 0.f, 0.f);
#pragma unroll
    for (int c = 0; c < 16; ++c) {
        float4 v = p[(size_t)c * TOT4 + i4];
        acc.x += v.x; acc.y += v.y; acc.z += v.z; acc.w += v.w;
    }
    float4 b = ((const float4*)bias)[i4 & 31];
    acc.x += b.x; acc.y += b.y; acc.z += b.z; acc.w += b.w;
    ((float4*)out)[i4] = acc;
}

// ---- segmented pool over sorted batch ----
__global__ __launch_bounds__(128) void pool_seg_kernel(const float* __restrict__ h,
                                                       const int* __restrict__ gstart,
                                                       float* __restrict__ g) {
    int gr = blockIdx.x;
    int t = threadIdx.x;
    int beg = gstart[gr];
    int end = gstart[gr + 1];
    float acc = 0.f;
    for (int r = beg; r < end; ++r) acc += h[(size_t)r * 128 + t];
    g[(size_t)gr * 128 + t] = acc;
}

extern "C" void kernel_launch(void* const* d_in, const int* in_sizes, int n_in, void* d_out,
                              int out_size, void* d_ws, size_t ws_size, hipStream_t stream) {
    const float* x = (const float*)d_in[0];
    const int* ei = (const int*)d_in[1];
    const int* batch = (const int*)d_in[2];
    const int* srcA = ei;
    const int* dstA = ei + NEDGES;

    const float* g0_w1 = (const float*)d_in[3];
    const float* g0_b1 = (const float*)d_in[4];
    const float* g0_ga = (const float*)d_in[5];
    const float* g0_be = (const float*)d_in[6];
    const float* g0_w2 = (const float*)d_in[7];
    const float* g0_b2 = (const float*)d_in[8];
    const float* g1_w1 = (const float*)d_in[9];
    const float* g1_b1 = (const float*)d_in[10];
    const float* g1_ga = (const float*)d_in[11];
    const float* g1_be = (const float*)d_in[12];
    const float* g1_w2 = (const float*)d_in[13];
    const float* g1_b2 = (const float*)d_in[14];
    const float* g2_w1 = (const float*)d_in[15];
    const float* g2_b1 = (const float*)d_in[16];
    const float* g2_ga = (const float*)d_in[17];
    const float* g2_be = (const float*)d_in[18];
    const float* g2_w2 = (const float*)d_in[19];
    const float* g2_b2 = (const float*)d_in[20];
    const float* fc0_w = (const float*)d_in[21];
    const float* fc0_b = (const float*)d_in[22];
    const float* fc1_w = (const float*)d_in[23];
    const float* fc1_b = (const float*)d_in[24];

    // --- workspace layout (~224 MB) ---
    float* ws = (float*)d_ws;
    const size_t BUF = (size_t)NNODES * 256;
    float* R0 = ws;
    float* R1 = R0 + BUF;  // also fc1 split-K partial buffer
    float* stats = R1 + BUF;                         // 512
    float* scsh = stats + 512;                       // 512
    float* g = scsh + 512;                           // 2048*128 pooled
    float* gh = g + (size_t)NGRAPHS * 128;           // 2048*1024 fc hidden
    int* deg = (int*)(gh + (size_t)NGRAPHS * 1024);  // NNODES
    int* rowptr = deg + NNODES;                      // NNODES+1
    int* cursor = rowptr + NNODES + 4;               // NNODES
    int* adj = cursor + NNODES;                      // NEDGES
    int* partials = adj + NEDGES;                    // 391
    int* gstart = partials + 512;                    // NGRAPHS+1
    // W-fragment slots: 6 x (65536 hi + 65536 lo) shorts, 16B-aligned
    short* wf = (short*)(gstart + 2052);
    short* whi[6];
    short* wlo[6];
    for (int i = 0; i < 6; ++i) {
        whi[i] = wf + (size_t)i * 131072;
        wlo[i] = whi[i] + 65536;
    }

    const int GB = (NNODES + 63) / 64;    // 1563 mfma-GEMM row-blocks
    const int NB = (NNODES + 255) / 256;  // 391 scan blocks

    // --- build CSR + graph bounds once ---
    hipMemsetAsync(deg, 0, NNODES * sizeof(int), stream);
    hipMemsetAsync(stats, 0, 512 * sizeof(float), stream);  // bnfinal re-zeroes thereafter
    deg_kernel<<<(NEDGES + 255) / 256, 256, 0, stream>>>(dstA, deg);
    scan1_kernel<<<NB, 256, 0, stream>>>(deg, partials);
    scan2_kernel<<<1, 512, 0, stream>>>(partials, NB);
    scan3_kernel<<<NB, 256, 0, stream>>>(deg, partials, rowptr, cursor, batch, gstart);
    fill_kernel<<<(NEDGES + 255) / 256, 256, 0, stream>>>(srcA, dstA, cursor, adj);

    // --- W-fragment pre-passes (hi/lo bf16 decomposition, fragment order) ---
    // (W, Kw, N, KT): L0g1(66,128,3) L0g2(128,128,4) L1g1(128,256,4) L1g2(256,256,8)
    //                 L2g1(256,128,8) L2g2(128,128,4)
    wprep_kernel<<<(8 * 3 * 512 + 255) / 256, 256, 0, stream>>>(g0_w1, 66, 128, 3, whi[0], wlo[0]);
    wprep_kernel<<<(8 * 4 * 512 + 255) / 256, 256, 0, stream>>>(g0_w2, 128, 128, 4, whi[1], wlo[1]);
    wprep_kernel<<<(16 * 4 * 512 + 255) / 256, 256, 0, stream>>>(g1_w1, 128, 256, 4, whi[2], wlo[2]);
    wprep_kernel<<<(16 * 8 * 512 + 255) / 256, 256, 0, stream>>>(g1_w2, 256, 256, 8, whi[3], wlo[3]);
    wprep_kernel<<<(8 * 8 * 512 + 255) / 256, 256, 0, stream>>>(g2_w1, 256, 128, 8, whi[4], wlo[4]);
    wprep_kernel<<<(8 * 4 * 512 + 255) / 256, 256, 0, stream>>>(g2_w2, 128, 128, 4, whi[5], wlo[5]);

    // ================= Layer 0 (66 -> 128 -> 128) =================
    gather_kernel<66, 2, 68><<<(NNODES * 33 + 255) / 256, 256, 0, stream>>>(x, rowptr, adj, R0,
                                                                            nullptr);
    gemm_mfma_kernel<8, false, false, true><<<GB, 256, 0, stream>>>(
        R0, whi[0], wlo[0], g0_b1, nullptr, R1, stats, NNODES, 68, 3, 128);
    bnfinal_kernel<<<1, 256, 0, stream>>>(stats, g0_ga, g0_be, scsh, 128, 1.0f / NNODES);
    gemm_mfma_kernel<8, true, true, false><<<GB, 256, 0, stream>>>(
        R1, whi[1], wlo[1], g0_b2, scsh, R0, nullptr, NNODES, 128, 4, 128);

    // ================= Layer 1 (128 -> 256 -> 256) =================
    gather_kernel<128, 4, 128><<<(NNODES * 32 + 255) / 256, 256, 0, stream>>>(R0, rowptr, adj, R1,
                                                                              nullptr);
    gemm_mfma_kernel<16, false, false, true><<<GB, 256, 0, stream>>>(
        R1, whi[2], wlo[2], g1_b1, nullptr, R0, stats, NNODES, 128, 4, 256);
    bnfinal_kernel<<<1, 256, 0, stream>>>(stats, g1_ga, g1_be, scsh, 256, 1.0f / NNODES);
    gemm_mfma_kernel<16, true, true, false><<<GB, 256, 0, stream>>>(
        R0, whi[3], wlo[3], g1_b2, scsh, R1, nullptr, NNODES, 256, 8, 256);

    // ================= Layer 2 (256 -> 128 -> 128), REORDERED =================
    gemm_mfma_kernel<8, false, false, false><<<GB, 256, 0, stream>>>(
        R1, whi[4], wlo[4], nullptr, nullptr, R0, nullptr, NNODES, 256, 8, 128);
    gather_kernel<128, 4, 128><<<(NNODES * 32 + 255) / 256, 256, 0, stream>>>(R0, rowptr, adj, R1,
                                                                              g2_b1);
    bnstats_kernel<128><<<128, 256, 0, stream>>>(R1, stats);
    bnfinal_kernel<<<1, 256, 0, stream>>>(stats, g2_ga, g2_be, scsh, 128, 1.0f / NNODES);
    gemm_mfma_kernel<8, true, true, false><<<GB, 256, 0, stream>>>(
        R1, whi[5], wlo[5], g2_b2, scsh, R0, nullptr, NNODES, 128, 4, 128);

    // ================= pool + FC head =================
    pool_seg_kernel<<<NGRAPHS, 128, 0, stream>>>(R0, gstart, g);

    gemm64_kernel<true, false><<<dim3(NGRAPHS / 64, 1024 / 64), 256, 0, stream>>>(
        g, fc0_w, fc0_b, gh, NGRAPHS, 128, 1024);
    gemm64_kernel<false, true><<<dim3(NGRAPHS / 64, 128 / 64, 16), 256, 0, stream>>>(
        gh, fc1_w, nullptr, R1, NGRAPHS, 1024, 128);
    splitk_reduce_kernel<<<(NGRAPHS * 128 / 4 + 255) / 256, 256, 0, stream>>>(R1, fc1_b,
                                                                              (float*)d_out);
}